// Round 1
// baseline (2251.130 us; speedup 1.0000x reference)
//
#include <hip/hip_runtime.h>
#include <stdint.h>

#define NROWS 8192
#define KDIM  1024
#define CAP   512
#define NEGBIG (-9.0e15f)
#define ADM_THR 20.0f
#define GOFF   65536
#define SMEMSZ 98304

typedef __attribute__((ext_vector_type(8))) __bf16 bf16x8;
typedef __attribute__((ext_vector_type(4))) float f32x4;
typedef __attribute__((ext_vector_type(4))) unsigned short us4;
typedef unsigned short u16;

__device__ __forceinline__ u16 f2bf(float f) {
  unsigned u = __float_as_uint(f);
  u += 0x7fffu + ((u >> 16) & 1u);
  return (u16)(u >> 16);
}
__device__ __forceinline__ float bf2f(u16 h) {
  return __uint_as_float(((unsigned)h) << 16);
}

__device__ __forceinline__ void glds16(const void* g, const char* lds) {
  __builtin_amdgcn_global_load_lds(
      (const __attribute__((address_space(1))) unsigned int*)(uintptr_t)g,
      (__attribute__((address_space(3))) unsigned int*)(uintptr_t)lds, 16, 0, 0);
}

__device__ __forceinline__ f32x4 mfma16(bf16x8 a, bf16x8 b, f32x4 c) {
  return __builtin_amdgcn_mfma_f32_16x16x32_bf16(a, b, c, 0, 0, 0);
}

// ---------------------------------------------------------------------------
// Unified GEMM core.
//   C[M][N] = A @ B^T, A = (ah, al) bf16 hi/lo [M][1024] row-major,
//   B rows = (bh, bl) bf16 hi/lo [brows][1024] row-major (row = output col).
// SCORES=false: one 32x128 output tile per wg (grid.y = col block),
//   epilogue adds bias and writes bf16 hi (/lo) C.
// SCORES=true: wg owns 32 rows, loops over all 8192 B-rows (keys) in chunks
//   of 128; epilogue per chunk does relu+adjacency mask, tracks wave-local
//   running row max, and emits candidates with S > max-20 (superset of all
//   entries with true softmax weight > e^-20).
// LDS: [0,64K)  A-hi slab, layout kb*2048 + kg*512 + row*16 (16B units)
//      [64K,96K) B stream double buffer; per buffer: hi 8KB then lo 8KB,
//                layout (key/32)*2048 + kg*512 + (key%32)*16
// A-lo lives in 128 VGPRs (flr[32]), indexed only by unrolled constants.
// ---------------------------------------------------------------------------
template<bool SCORES, int NSPLIT, bool SPLITOUT>
__global__ __launch_bounds__(512, 2) void core_kernel(
    const u16* __restrict__ ah, const u16* __restrict__ al,
    const u16* __restrict__ bh, const u16* __restrict__ bl,
    const float* __restrict__ bias, u16* __restrict__ ch, u16* __restrict__ cl,
    const int* __restrict__ adj, float* __restrict__ candS,
    int* __restrict__ candK, int* __restrict__ cnts)
{
  extern __shared__ char smem[];
  const int tid = threadIdx.x;
  const int w = tid >> 6, lane = tid & 63;
  const int rt = w & 1;        // row tile (16 rows) within the 32-row slab
  const int kc = w >> 1;       // 32-key column group within the 128-key chunk
  const int growbase = blockIdx.x * 32;

  // ---- stage A-hi into LDS (linear: s*16 == kb*2048 + kg*512 + row*16)
  for (int s = tid; s < 4096; s += 512) {
    int kb = s >> 7, kg = (s >> 5) & 3, row = s & 31;
    bf16x8 v = *(const bf16x8*)(ah + (size_t)(growbase + row) * KDIM + kb * 32 + kg * 8);
    *(bf16x8*)(smem + s * 16) = v;
  }

  // ---- preload A-lo fragments into registers (NSPLIT==3 only)
  bf16x8 flr[32];
  if constexpr (NSPLIT == 3) {
    const u16* base = al + (size_t)(growbase + rt * 16 + (lane & 15)) * KDIM + ((lane >> 4) << 3);
    #pragma unroll
    for (int kk = 0; kk < 32; ++kk) flr[kk] = *(const bf16x8*)(base + kk * 32);
  }

  // ---- B staging geometry (global_load_lds: per-lane src, uniform LDS base)
  const int w4 = w & 3;
  const int breg = w >> 2;                 // 0 -> hi region, 1 -> lo region
  const u16* bsrc = breg ? bl : bh;
  const int s0 = w4 * 128 + lane, s1 = s0 + 64;
  const int br0 = (s0 >> 7) * 32 + (s0 & 31), bc0 = ((s0 >> 5) & 3) * 8;
  const int br1 = (s1 >> 7) * 32 + (s1 & 31), bc1 = ((s1 >> 5) & 3) * 8;
  char* lds0 = smem + GOFF + breg * 8192 + w4 * 2048;

  // ---- fragment read offsets
  const int aoff = ((lane >> 4) << 9) + ((rt << 4) + (lane & 15)) * 16;
  const int kt0 = kc * 2, kt1 = kc * 2 + 1;
  const int boff0 = ((kt0 >> 1) << 11) + ((lane >> 4) << 9) + (((kt0 & 1) << 4) + (lane & 15)) * 16;
  const int boff1 = ((kt1 >> 1) << 11) + ((lane >> 4) << 9) + (((kt1 & 1) << 4) + (lane & 15)) * 16;

  const int nchunk = SCORES ? (NROWS / 128) : 1;
  const int cfix = SCORES ? 0 : blockIdx.y;

  auto stage = [&](int brow0, int kk, int p) {
    glds16(bsrc + (size_t)(brow0 + br0) * KDIM + kk * 32 + bc0, lds0 + p * 16384);
    glds16(bsrc + (size_t)(brow0 + br1) * KDIM + kk * 32 + bc1, lds0 + p * 16384 + 1024);
  };

  // prologue: stage (chunk 0, kstep 0) into buffer 0
  stage(cfix * 128, 0, 0);
  asm volatile("s_waitcnt vmcnt(0)" ::: "memory");
  __syncthreads();

  float mrun[4] = {NEGBIG, NEGBIG, NEGBIG, NEGBIG};

  for (int c = 0; c < nchunk; ++c) {
    const int cc = SCORES ? c : cfix;
    f32x4 acc0 = {0.f, 0.f, 0.f, 0.f};
    f32x4 acc1 = {0.f, 0.f, 0.f, 0.f};
    #pragma unroll
    for (int kk = 0; kk < 32; ++kk) {
      const int p = kk & 1;
      if (kk < 31) stage(cc * 128, kk + 1, p ^ 1);
      else if (SCORES && (c + 1 < nchunk)) stage((c + 1) * 128, 0, p ^ 1);

      bf16x8 ahf = *(const bf16x8*)(smem + kk * 2048 + aoff);
      const char* gb = smem + GOFF + p * 16384;
      bf16x8 b0 = *(const bf16x8*)(gb + boff0);
      bf16x8 b1 = *(const bf16x8*)(gb + boff1);
      if constexpr (NSPLIT == 3) {
        bf16x8 l0 = *(const bf16x8*)(gb + 8192 + boff0);
        bf16x8 l1 = *(const bf16x8*)(gb + 8192 + boff1);
        acc0 = mfma16(flr[kk], b0, acc0);
        acc0 = mfma16(ahf, l0, acc0);
        acc1 = mfma16(flr[kk], b1, acc1);
        acc1 = mfma16(ahf, l1, acc1);
      }
      acc0 = mfma16(ahf, b0, acc0);
      acc1 = mfma16(ahf, b1, acc1);

      asm volatile("s_waitcnt vmcnt(0)" ::: "memory");
      __syncthreads();
    }

    if constexpr (SCORES) {
      const int rb = growbase + rt * 16 + ((lane >> 4) << 2);
      const int keyb = cc * 128 + kc * 32 + (lane & 15);
      float sm0[4], sm1[4];
      #pragma unroll
      for (int j = 0; j < 4; ++j) {
        float v0 = acc0[j] > 0.f ? acc0[j] : 0.f;   // relu
        float v1 = acc1[j] > 0.f ? acc1[j] : 0.f;
        int a0 = adj[(size_t)(rb + j) * NROWS + keyb];
        int a1 = adj[(size_t)(rb + j) * NROWS + keyb + 16];
        sm0[j] = a0 > 0 ? v0 : NEGBIG;              // adjacency mask
        sm1[j] = a1 > 0 ? v1 : NEGBIG;
      }
      #pragma unroll
      for (int j = 0; j < 4; ++j) {                 // per-row running max
        float rm = fmaxf(sm0[j], sm1[j]);
        rm = fmaxf(rm, __shfl_xor(rm, 1));
        rm = fmaxf(rm, __shfl_xor(rm, 2));
        rm = fmaxf(rm, __shfl_xor(rm, 4));
        rm = fmaxf(rm, __shfl_xor(rm, 8));
        mrun[j] = fmaxf(mrun[j], rm);
      }
      #pragma unroll
      for (int j = 0; j < 4; ++j) {                 // candidate emission
        float thr = mrun[j] - ADM_THR;
        if (sm0[j] > thr) {
          int pos = atomicAdd(cnts + (rb + j), 1);
          if (pos < CAP) { candS[(size_t)(rb + j) * CAP + pos] = sm0[j];
                           candK[(size_t)(rb + j) * CAP + pos] = keyb; }
        }
        if (sm1[j] > thr) {
          int pos = atomicAdd(cnts + (rb + j), 1);
          if (pos < CAP) { candS[(size_t)(rb + j) * CAP + pos] = sm1[j];
                           candK[(size_t)(rb + j) * CAP + pos] = keyb + 16; }
        }
      }
    } else {
      const int rowb = growbase + rt * 16 + ((lane >> 4) << 2);
      const int colb = cfix * 128 + kc * 32 + (lane & 15);
      float bi0 = bias[colb], bi1 = bias[colb + 16];
      #pragma unroll
      for (int j = 0; j < 4; ++j) {
        float v0 = acc0[j] + bi0, v1 = acc1[j] + bi1;
        u16 h0 = f2bf(v0), h1 = f2bf(v1);
        ch[(size_t)(rowb + j) * KDIM + colb] = h0;
        ch[(size_t)(rowb + j) * KDIM + colb + 16] = h1;
        if constexpr (SPLITOUT) {
          cl[(size_t)(rowb + j) * KDIM + colb] = f2bf(v0 - bf2f(h0));
          cl[(size_t)(rowb + j) * KDIM + colb + 16] = f2bf(v1 - bf2f(h1));
        }
      }
    }
  }
}

// ---------------------------------------------------------------------------
// Exact softmax over candidates + weighted gather of v rows. One row / block.
// ---------------------------------------------------------------------------
__global__ __launch_bounds__(256) void finalize_kernel(
    const float* __restrict__ candS, const int* __restrict__ candK,
    const int* __restrict__ cnts, const u16* __restrict__ vh,
    float* __restrict__ out)
{
  const int row = blockIdx.x, tid = threadIdx.x;
  __shared__ float sS[CAP];
  __shared__ int sK[CAP];
  __shared__ float red[8];
  int cnt = cnts[row]; cnt = cnt < CAP ? cnt : CAP;
  const int col = tid * 4;
  if (cnt <= 0) {                       // all-masked row: unreachable for this data
    f32x4 z = {0.f, 0.f, 0.f, 0.f};
    *(f32x4*)(out + (size_t)row * KDIM + col) = z;
    return;
  }
  for (int i = tid; i < cnt; i += 256) {
    sS[i] = candS[(size_t)row * CAP + i];
    sK[i] = candK[(size_t)row * CAP + i];
  }
  __syncthreads();
  float lm = NEGBIG;
  for (int i = tid; i < cnt; i += 256) lm = fmaxf(lm, sS[i]);
  #pragma unroll
  for (int d = 1; d < 64; d <<= 1) lm = fmaxf(lm, __shfl_xor(lm, d));
  if ((tid & 63) == 0) red[tid >> 6] = lm;
  __syncthreads();
  const float m = fmaxf(fmaxf(red[0], red[1]), fmaxf(red[2], red[3]));
  __syncthreads();
  float ls = 0.f;
  for (int i = tid; i < cnt; i += 256) {
    float wv = __expf(sS[i] - m);
    sS[i] = wv;
    ls += wv;
  }
  #pragma unroll
  for (int d = 1; d < 64; d <<= 1) ls += __shfl_xor(ls, d);
  if ((tid & 63) == 0) red[tid >> 6] = ls;
  __syncthreads();
  const float inv = 1.f / (red[0] + red[1] + red[2] + red[3]);
  float a0 = 0.f, a1 = 0.f, a2 = 0.f, a3 = 0.f;
  const u16* vbase = vh + col;
  for (int i = 0; i < cnt; ++i) {
    float wv = sS[i];
    us4 vv = *(const us4*)(vbase + (size_t)sK[i] * KDIM);
    a0 += wv * bf2f(vv[0]); a1 += wv * bf2f(vv[1]);
    a2 += wv * bf2f(vv[2]); a3 += wv * bf2f(vv[3]);
  }
  f32x4 o = {a0 * inv, a1 * inv, a2 * inv, a3 * inv};
  *(f32x4*)(out + (size_t)row * KDIM + col) = o;
}

// ---------------------------------------------------------------------------
// Transpose + hi/lo split of a [K][N] fp32 weight into [N][K] bf16 pair.
// ---------------------------------------------------------------------------
__global__ __launch_bounds__(256) void wsplit_kernel(
    const float* __restrict__ W, u16* __restrict__ th, u16* __restrict__ tl)
{
  __shared__ float tile[32][33];
  const int bx = blockIdx.x, by = blockIdx.y;
  const int tx = threadIdx.x & 31, ty = threadIdx.x >> 5;
  #pragma unroll
  for (int i = 0; i < 4; ++i) {
    int ky = ty + i * 8;
    tile[ky][tx] = W[(size_t)(by * 32 + ky) * KDIM + bx * 32 + tx];
  }
  __syncthreads();
  #pragma unroll
  for (int i = 0; i < 4; ++i) {
    int ny = ty + i * 8;
    float v = tile[tx][ny];                 // = W[by*32+tx][bx*32+ny]
    u16 h = f2bf(v);
    th[(size_t)(bx * 32 + ny) * KDIM + by * 32 + tx] = h;
    tl[(size_t)(bx * 32 + ny) * KDIM + by * 32 + tx] = f2bf(v - bf2f(h));
  }
}

__global__ __launch_bounds__(256) void xsplit_kernel(
    const float* __restrict__ x, u16* __restrict__ xh, u16* __restrict__ xl)
{
  size_t i = ((size_t)blockIdx.x * 256 + threadIdx.x) * 4;
  f32x4 v = *(const f32x4*)(x + i);
  us4 h, l;
  #pragma unroll
  for (int j = 0; j < 4; ++j) {
    h[j] = f2bf(v[j]);
    l[j] = f2bf(v[j] - bf2f(h[j]));
  }
  *(us4*)(xh + i) = h;
  *(us4*)(xl + i) = l;
}

// Fallback: encode ws_size into the output so an undersized workspace is
// diagnosable from the reported absmax.
__global__ void ws_report(float* out, size_t n, float v) {
  for (size_t i = (size_t)blockIdx.x * blockDim.x + threadIdx.x; i < n;
       i += (size_t)gridDim.x * blockDim.x) out[i] = v;
}

extern "C" void kernel_launch(void* const* d_in, const int* in_sizes, int n_in,
                              void* d_out, int out_size, void* d_ws, size_t ws_size,
                              hipStream_t stream) {
  (void)in_sizes; (void)n_in;
  const float* x   = (const float*)d_in[0];
  const int*   adj = (const int*)d_in[1];
  const float* Wf  = (const float*)d_in[2];
  const float* bf_ = (const float*)d_in[3];
  const float* Wg  = (const float*)d_in[4];
  const float* bg_ = (const float*)d_in[5];
  const float* W   = (const float*)d_in[6];
  const float* bW_ = (const float*)d_in[7];

  char* p = (char*)d_ws;
  const size_t ND2 = (size_t)NROWS * KDIM * 2;
  const size_t W2  = (size_t)KDIM * KDIM * 2;
  u16* xh = (u16*)p;  p += ND2;
  u16* xl = (u16*)p;  p += ND2;
  u16* fh = (u16*)p;  p += ND2;
  u16* fl = (u16*)p;  p += ND2;
  u16* gh = (u16*)p;  p += ND2;
  u16* gl = (u16*)p;  p += ND2;
  u16* vh = (u16*)p;  p += ND2;
  u16* wfh = (u16*)p; p += W2;
  u16* wfl = (u16*)p; p += W2;
  u16* wgh = (u16*)p; p += W2;
  u16* wgl = (u16*)p; p += W2;
  u16* wh  = (u16*)p; p += W2;
  u16* wl  = (u16*)p; p += W2;
  float* candS = (float*)p; p += (size_t)NROWS * CAP * 4;
  int*   candK = (int*)p;   p += (size_t)NROWS * CAP * 4;
  int*   cnts  = (int*)p;   p += (size_t)NROWS * 4;
  const size_t need = (size_t)(p - (char*)d_ws);
  if (ws_size < need) {
    ws_report<<<256, 256, 0, stream>>>((float*)d_out, (size_t)out_size, (float)ws_size);
    return;
  }

  auto kf = core_kernel<false, 3, true>;
  auto kv = core_kernel<false, 1, false>;
  auto ks = core_kernel<true, 3, false>;
  hipFuncSetAttribute((const void*)kf, hipFuncAttributeMaxDynamicSharedMemorySize, SMEMSZ);
  hipFuncSetAttribute((const void*)kv, hipFuncAttributeMaxDynamicSharedMemorySize, SMEMSZ);
  hipFuncSetAttribute((const void*)ks, hipFuncAttributeMaxDynamicSharedMemorySize, SMEMSZ);

  hipMemsetAsync(cnts, 0, (size_t)NROWS * 4, stream);
  wsplit_kernel<<<dim3(32, 32), 256, 0, stream>>>(Wf, wfh, wfl);
  wsplit_kernel<<<dim3(32, 32), 256, 0, stream>>>(Wg, wgh, wgl);
  wsplit_kernel<<<dim3(32, 32), 256, 0, stream>>>(W, wh, wl);
  xsplit_kernel<<<(NROWS * KDIM) / (256 * 4), 256, 0, stream>>>(x, xh, xl);

  // f = x@Wf + bf (split-3), g = x@Wg + bg (split-3), v = x@W + bW (1 pass)
  kf<<<dim3(256, 8), 512, SMEMSZ, stream>>>(xh, xl, wfh, wfl, bf_, fh, fl,
                                            nullptr, nullptr, nullptr, nullptr);
  kf<<<dim3(256, 8), 512, SMEMSZ, stream>>>(xh, xl, wgh, wgl, bg_, gh, gl,
                                            nullptr, nullptr, nullptr, nullptr);
  kv<<<dim3(256, 8), 512, SMEMSZ, stream>>>(xh, xl, wh, wl, bW_, vh, nullptr,
                                            nullptr, nullptr, nullptr, nullptr);
  // scores sweep: relu(f@g^T), mask, candidate emission
  ks<<<dim3(256, 1), 512, SMEMSZ, stream>>>(fh, fl, gh, gl, nullptr, nullptr, nullptr,
                                            adj, candS, candK, cnts);
  // exact softmax over candidates + weighted gather of v rows
  finalize_kernel<<<NROWS, 256, 0, stream>>>(candS, candK, cnts, vh, (float*)d_out);
}

// Round 2
// 1654.951 us; speedup vs baseline: 1.3602x; 1.3602x over previous
//
#include <hip/hip_runtime.h>
#include <stdint.h>

#define NROWS 8192
#define KDIM  1024
#define CAP   512
#define NEGBIG (-9.0e15f)
#define ADM_THR 20.0f
#define GOFF   65536
#define SM3    131072   // A-hi 64K + 4-buffer B ring (hi+lo) 64K
#define SM1    98304    // A-hi 64K + 4-buffer B ring (hi only) 32K

typedef __attribute__((ext_vector_type(8))) __bf16 bf16x8;
typedef __attribute__((ext_vector_type(4))) float f32x4;
typedef __attribute__((ext_vector_type(4))) unsigned short us4;
typedef __attribute__((ext_vector_type(4))) int i32x4;
typedef unsigned short u16;

__device__ __forceinline__ u16 f2bf(float f) {
  unsigned u = __float_as_uint(f);
  u += 0x7fffu + ((u >> 16) & 1u);
  return (u16)(u >> 16);
}
__device__ __forceinline__ float bf2f(u16 h) {
  return __uint_as_float(((unsigned)h) << 16);
}

__device__ __forceinline__ void glds16(const void* g, const char* lds) {
  __builtin_amdgcn_global_load_lds(
      (const __attribute__((address_space(1))) unsigned int*)(uintptr_t)g,
      (__attribute__((address_space(3))) unsigned int*)(uintptr_t)lds, 16, 0, 0);
}

__device__ __forceinline__ f32x4 mfma16(bf16x8 a, bf16x8 b, f32x4 c) {
  return __builtin_amdgcn_mfma_f32_16x16x32_bf16(a, b, c, 0, 0, 0);
}

// ---------------------------------------------------------------------------
// Unified GEMM core, software-pipelined (T3+T4):
//   4-buffer LDS ring for the B stream, counted vmcnt (never 0 mid-loop),
//   raw s_barriers. Per phase:
//     ds_read frags(buf t%4) ; issue stage(t+3) ; s_waitcnt vmcnt(4) ;
//     s_barrier ; MFMA ; s_waitcnt lgkmcnt(0) ; s_barrier
//   RAW: stage(t) completion is published by phase t-1's vmcnt+barrier.
//   WAR: stage(t+3) overwrites buf read at phase t-1, whose ds_reads were
//        drained by phase t-1's lgkmcnt(0)+barrier.
// SCORES=true: adjacency comes as a bitmask word per (row, 32-key group),
//   emission uses one ballot-compacted atomicAdd per 16-lane row group.
// ---------------------------------------------------------------------------
template<bool SCORES, int NSPLIT, bool SPLITOUT>
__global__ __launch_bounds__(512, 2) void core_kernel(
    const u16* __restrict__ ah, const u16* __restrict__ al,
    const u16* __restrict__ bh, const u16* __restrict__ bl,
    const float* __restrict__ bias, u16* __restrict__ ch, u16* __restrict__ cl,
    const uint32_t* __restrict__ adjb, float* __restrict__ candS,
    int* __restrict__ candK, int* __restrict__ cnts)
{
  extern __shared__ char smem[];
  constexpr int BUFB = (NSPLIT == 3) ? 16384 : 8192;
  const int tid = threadIdx.x;
  const int w = tid >> 6, lane = tid & 63;
  const int rt = w & 1;        // row tile (16 rows) within the 32-row slab
  const int kc = w >> 1;       // 32-key column group within the 128-key chunk
  const int growbase = blockIdx.x * 32;

  // ---- stage A-hi into LDS (slot s -> kb*2048 + kg*512 + row*16)
  for (int s = tid; s < 4096; s += 512) {
    int kb = s >> 7, kg = (s >> 5) & 3, row = s & 31;
    bf16x8 v = *(const bf16x8*)(ah + (size_t)(growbase + row) * KDIM + kb * 32 + kg * 8);
    *(bf16x8*)(smem + s * 16) = v;
  }

  // ---- A-lo fragments (compiler may keep in regs or re-load from L1/L2)
  bf16x8 flr[32];
  if constexpr (NSPLIT == 3) {
    const u16* base = al + (size_t)(growbase + rt * 16 + (lane & 15)) * KDIM + ((lane >> 4) << 3);
    #pragma unroll
    for (int kk = 0; kk < 32; ++kk) flr[kk] = *(const bf16x8*)(base + kk * 32);
  }

  // ---- B staging geometry (glds: per-lane global src, uniform LDS base)
  int s0 = 0, s1 = 0;
  const u16* bsrc;
  char* lds0;
  if constexpr (NSPLIT == 3) {
    const int w4 = w & 3, breg = w >> 2;   // waves 0-3 stage hi, 4-7 stage lo
    bsrc = breg ? bl : bh;
    s0 = w4 * 128 + lane; s1 = s0 + 64;
    lds0 = smem + GOFF + breg * 8192 + w4 * 2048;
  } else {
    bsrc = bh;
    s0 = w * 64 + lane;
    lds0 = smem + GOFF + w * 1024;
  }
  const int br0 = (s0 >> 7) * 32 + (s0 & 31), bc0 = ((s0 >> 5) & 3) * 8;
  const int br1 = (s1 >> 7) * 32 + (s1 & 31), bc1 = ((s1 >> 5) & 3) * 8;

  // ---- fragment read offsets
  const int aoff = ((lane >> 4) << 9) + ((rt << 4) + (lane & 15)) * 16;
  const int kt0 = kc * 2, kt1 = kc * 2 + 1;
  const int boff0 = ((kt0 >> 1) << 11) + ((lane >> 4) << 9) + (((kt0 & 1) << 4) + (lane & 15)) * 16;
  const int boff1 = ((kt1 >> 1) << 11) + ((lane >> 4) << 9) + (((kt1 & 1) << 4) + (lane & 15)) * 16;

  const int nchunk = SCORES ? (NROWS / 128) : 1;
  const int cfix = SCORES ? 0 : blockIdx.y;

  auto stage = [&](int cc_, int kk_, int buf_) {
    glds16(bsrc + (size_t)(cc_ * 128 + br0) * KDIM + kk_ * 32 + bc0, lds0 + buf_ * BUFB);
    if constexpr (NSPLIT == 3)
      glds16(bsrc + (size_t)(cc_ * 128 + br1) * KDIM + kk_ * 32 + bc1, lds0 + buf_ * BUFB + 1024);
  };

  // prologue: fill ring buffers 0..2; full sync (one-time drain is fine)
  stage(cfix, 0, 0);
  stage(cfix, 1, 1);
  stage(cfix, 2, 2);
  __syncthreads();

  float mrun[4] = {NEGBIG, NEGBIG, NEGBIG, NEGBIG};
  const int rb0 = growbase + rt * 16 + ((lane >> 4) << 2);

  for (int c = 0; c < nchunk; ++c) {
    const int cc = SCORES ? c : cfix;

    uint32_t aw[4] = {0, 0, 0, 0};
    if constexpr (SCORES) {
      #pragma unroll
      for (int j = 0; j < 4; ++j)
        aw[j] = adjb[(size_t)(rb0 + j) * (NROWS / 32) + cc * 4 + kc];
    }

    f32x4 acc0 = {0.f, 0.f, 0.f, 0.f};
    f32x4 acc1 = {0.f, 0.f, 0.f, 0.f};
    #pragma unroll
    for (int kk = 0; kk < 32; ++kk) {
      const int buf = kk & 3;
      // (A) fragment reads from the ring buffer staged 3 phases ago
      bf16x8 ahf = *(const bf16x8*)(smem + kk * 2048 + aoff);
      const char* gb = smem + GOFF + buf * BUFB;
      bf16x8 b0 = *(const bf16x8*)(gb + boff0);
      bf16x8 b1 = *(const bf16x8*)(gb + boff1);
      bf16x8 l0, l1;
      if constexpr (NSPLIT == 3) {
        l0 = *(const bf16x8*)(gb + 8192 + boff0);
        l1 = *(const bf16x8*)(gb + 8192 + boff1);
      }
      // (B) issue stage(t+3), (C) counted wait ensuring stage(t+1) landed
      if (kk < 29) {
        stage(cc, kk + 3, (kk + 3) & 3);
        if constexpr (NSPLIT == 3) asm volatile("s_waitcnt vmcnt(4)" ::: "memory");
        else                       asm volatile("s_waitcnt vmcnt(2)" ::: "memory");
      } else if (SCORES && c + 1 < nchunk) {
        stage(cc + 1, kk - 29, (kk + 3) & 3);
        if constexpr (NSPLIT == 3) asm volatile("s_waitcnt vmcnt(4)" ::: "memory");
        else                       asm volatile("s_waitcnt vmcnt(2)" ::: "memory");
      } else if (kk == 29) {
        if constexpr (NSPLIT == 3) asm volatile("s_waitcnt vmcnt(2)" ::: "memory");
        else                       asm volatile("s_waitcnt vmcnt(1)" ::: "memory");
      } else if (kk == 30) {
        asm volatile("s_waitcnt vmcnt(0)" ::: "memory");
      }
      // (D) publish: all waves' stage(t+1) complete past this barrier
      __builtin_amdgcn_s_barrier();
      // (E) MFMA (compiler inserts the lgkm data waits)
      if constexpr (NSPLIT == 3) {
        acc0 = mfma16(flr[kk], b0, acc0);
        acc0 = mfma16(ahf, l0, acc0);
        acc0 = mfma16(ahf, b0, acc0);
        acc1 = mfma16(flr[kk], b1, acc1);
        acc1 = mfma16(ahf, l1, acc1);
        acc1 = mfma16(ahf, b1, acc1);
      } else {
        acc0 = mfma16(ahf, b0, acc0);
        acc1 = mfma16(ahf, b1, acc1);
      }
      // (E2) drain own ds_reads so next phase's stage may overwrite, (F) barrier
      asm volatile("s_waitcnt lgkmcnt(0)" ::: "memory");
      __builtin_amdgcn_s_barrier();
    }

    if constexpr (SCORES) {
      const int keyb = cc * 128 + kc * 32 + (lane & 15);
      float sm0[4], sm1[4];
      #pragma unroll
      for (int j = 0; j < 4; ++j) {
        float v0 = acc0[j] > 0.f ? acc0[j] : 0.f;   // relu
        float v1 = acc1[j] > 0.f ? acc1[j] : 0.f;
        sm0[j] = ((aw[j] >> (lane & 15)) & 1u) ? v0 : NEGBIG;   // adjacency mask
        sm1[j] = ((aw[j] >> ((lane & 15) + 16)) & 1u) ? v1 : NEGBIG;
      }
      #pragma unroll
      for (int j = 0; j < 4; ++j) {                 // per-row running max (16-lane group)
        float rm = fmaxf(sm0[j], sm1[j]);
        rm = fmaxf(rm, __shfl_xor(rm, 1));
        rm = fmaxf(rm, __shfl_xor(rm, 2));
        rm = fmaxf(rm, __shfl_xor(rm, 4));
        rm = fmaxf(rm, __shfl_xor(rm, 8));
        mrun[j] = fmaxf(mrun[j], rm);
      }
      const unsigned long long lmask = (1ull << lane) - 1ull;
      const unsigned long long gm = 0xFFFFull << (lane & 48);
      #pragma unroll
      for (int j = 0; j < 4; ++j) {                 // ballot-compacted emission
        float thr = mrun[j] - ADM_THR;
        bool e0 = sm0[j] > thr, e1 = sm1[j] > thr;
        unsigned long long m0 = __ballot(e0), m1 = __ballot(e1);
        int n0 = __popcll(m0 & gm), n1 = __popcll(m1 & gm);
        int base = 0;
        if ((lane & 15) == 0 && (n0 + n1) > 0) base = atomicAdd(cnts + rb0 + j, n0 + n1);
        base = __shfl(base, lane & 48);
        int p0 = base + __popcll(m0 & gm & lmask);
        int p1 = base + n0 + __popcll(m1 & gm & lmask);
        if (e0 && p0 < CAP) { candS[(size_t)(rb0 + j) * CAP + p0] = sm0[j];
                              candK[(size_t)(rb0 + j) * CAP + p0] = keyb; }
        if (e1 && p1 < CAP) { candS[(size_t)(rb0 + j) * CAP + p1] = sm1[j];
                              candK[(size_t)(rb0 + j) * CAP + p1] = keyb + 16; }
      }
    } else {
      const int colb = cfix * 128 + kc * 32 + (lane & 15);
      float bi0 = bias[colb], bi1 = bias[colb + 16];
      #pragma unroll
      for (int j = 0; j < 4; ++j) {
        float v0 = acc0[j] + bi0, v1 = acc1[j] + bi1;
        u16 h0 = f2bf(v0), h1 = f2bf(v1);
        ch[(size_t)(rb0 + j) * KDIM + colb] = h0;
        ch[(size_t)(rb0 + j) * KDIM + colb + 16] = h1;
        if constexpr (SPLITOUT) {
          cl[(size_t)(rb0 + j) * KDIM + colb] = f2bf(v0 - bf2f(h0));
          cl[(size_t)(rb0 + j) * KDIM + colb + 16] = f2bf(v1 - bf2f(h1));
        }
      }
    }
  }
}

// ---------------------------------------------------------------------------
// adj (int32 0/1, 268 MB) -> bitmask (8 MB). Pure BW-bound single pass.
// word w covers keys [(w%256)*32, +32) of row w/256; bit b = key (w%256)*32+b.
// ---------------------------------------------------------------------------
__global__ __launch_bounds__(256) void adjpack_kernel(
    const int* __restrict__ adj, uint32_t* __restrict__ adjb)
{
  size_t w = (size_t)blockIdx.x * 256 + threadIdx.x;
  const int* src = adj + (w << 5);
  uint32_t m = 0;
  #pragma unroll
  for (int j = 0; j < 8; ++j) {
    i32x4 v = *(const i32x4*)(src + j * 4);
    m |= (v[0] > 0 ? 1u : 0u) << (j * 4)
       | (v[1] > 0 ? 1u : 0u) << (j * 4 + 1)
       | (v[2] > 0 ? 1u : 0u) << (j * 4 + 2)
       | (v[3] > 0 ? 1u : 0u) << (j * 4 + 3);
  }
  adjb[w] = m;
}

// ---------------------------------------------------------------------------
// Exact softmax over candidates; prune weights < 2e-8 (error <= ~5e-5), then
// weighted gather of v rows over the ~10 surviving candidates.
// ---------------------------------------------------------------------------
__global__ __launch_bounds__(256) void finalize_kernel(
    const float* __restrict__ candS, const int* __restrict__ candK,
    const int* __restrict__ cnts, const u16* __restrict__ vh,
    float* __restrict__ out)
{
  const int row = blockIdx.x, tid = threadIdx.x;
  __shared__ float sS[CAP];
  __shared__ int sK[CAP];
  __shared__ float sW2[CAP];
  __shared__ int sK2[CAP];
  __shared__ float red[4];
  __shared__ int nsig;
  int cnt = cnts[row]; cnt = cnt < CAP ? cnt : CAP;
  const int col = tid * 4;
  if (cnt <= 0) {
    f32x4 z = {0.f, 0.f, 0.f, 0.f};
    *(f32x4*)(out + (size_t)row * KDIM + col) = z;
    return;
  }
  if (tid == 0) nsig = 0;
  for (int i = tid; i < cnt; i += 256) {
    sS[i] = candS[(size_t)row * CAP + i];
    sK[i] = candK[(size_t)row * CAP + i];
  }
  __syncthreads();
  float lm = NEGBIG;
  for (int i = tid; i < cnt; i += 256) lm = fmaxf(lm, sS[i]);
  #pragma unroll
  for (int d = 1; d < 64; d <<= 1) lm = fmaxf(lm, __shfl_xor(lm, d));
  if ((tid & 63) == 0) red[tid >> 6] = lm;
  __syncthreads();
  const float m = fmaxf(fmaxf(red[0], red[1]), fmaxf(red[2], red[3]));
  __syncthreads();
  float ls = 0.f;
  for (int i = tid; i < cnt; i += 256) {
    float wv = __expf(sS[i] - m);
    ls += wv;
    if (wv > 2e-8f) {
      int p = atomicAdd(&nsig, 1);
      sW2[p] = wv; sK2[p] = sK[i];
    }
  }
  #pragma unroll
  for (int d = 1; d < 64; d <<= 1) ls += __shfl_xor(ls, d);
  if ((tid & 63) == 0) red[tid >> 6] = ls;
  __syncthreads();
  const float inv = 1.f / (red[0] + red[1] + red[2] + red[3]);
  const int ns = nsig;
  float a0 = 0.f, a1 = 0.f, a2 = 0.f, a3 = 0.f;
  const u16* vbase = vh + col;
  for (int i = 0; i < ns; ++i) {
    float wv = sW2[i];
    us4 vv = *(const us4*)(vbase + (size_t)sK2[i] * KDIM);
    a0 += wv * bf2f(vv[0]); a1 += wv * bf2f(vv[1]);
    a2 += wv * bf2f(vv[2]); a3 += wv * bf2f(vv[3]);
  }
  f32x4 o = {a0 * inv, a1 * inv, a2 * inv, a3 * inv};
  *(f32x4*)(out + (size_t)row * KDIM + col) = o;
}

// ---------------------------------------------------------------------------
// Transpose + hi/lo split of a [K][N] fp32 weight into [N][K] bf16 pair.
// ---------------------------------------------------------------------------
__global__ __launch_bounds__(256) void wsplit_kernel(
    const float* __restrict__ W, u16* __restrict__ th, u16* __restrict__ tl)
{
  __shared__ float tile[32][33];
  const int bx = blockIdx.x, by = blockIdx.y;
  const int tx = threadIdx.x & 31, ty = threadIdx.x >> 5;
  #pragma unroll
  for (int i = 0; i < 4; ++i) {
    int ky = ty + i * 8;
    tile[ky][tx] = W[(size_t)(by * 32 + ky) * KDIM + bx * 32 + tx];
  }
  __syncthreads();
  #pragma unroll
  for (int i = 0; i < 4; ++i) {
    int ny = ty + i * 8;
    float v = tile[tx][ny];                 // = W[by*32+tx][bx*32+ny]
    u16 h = f2bf(v);
    th[(size_t)(bx * 32 + ny) * KDIM + by * 32 + tx] = h;
    tl[(size_t)(bx * 32 + ny) * KDIM + by * 32 + tx] = f2bf(v - bf2f(h));
  }
}

__global__ __launch_bounds__(256) void xsplit_kernel(
    const float* __restrict__ x, u16* __restrict__ xh, u16* __restrict__ xl)
{
  size_t i = ((size_t)blockIdx.x * 256 + threadIdx.x) * 4;
  f32x4 v = *(const f32x4*)(x + i);
  us4 h, l;
  #pragma unroll
  for (int j = 0; j < 4; ++j) {
    h[j] = f2bf(v[j]);
    l[j] = f2bf(v[j] - bf2f(h[j]));
  }
  *(us4*)(xh + i) = h;
  *(us4*)(xl + i) = l;
}

// Fallback: encode ws_size into the output so an undersized workspace is
// diagnosable from the reported absmax.
__global__ void ws_report(float* out, size_t n, float v) {
  for (size_t i = (size_t)blockIdx.x * blockDim.x + threadIdx.x; i < n;
       i += (size_t)gridDim.x * blockDim.x) out[i] = v;
}

extern "C" void kernel_launch(void* const* d_in, const int* in_sizes, int n_in,
                              void* d_out, int out_size, void* d_ws, size_t ws_size,
                              hipStream_t stream) {
  (void)in_sizes; (void)n_in;
  const float* x   = (const float*)d_in[0];
  const int*   adj = (const int*)d_in[1];
  const float* Wf  = (const float*)d_in[2];
  const float* bf_ = (const float*)d_in[3];
  const float* Wg  = (const float*)d_in[4];
  const float* bg_ = (const float*)d_in[5];
  const float* W   = (const float*)d_in[6];
  const float* bW_ = (const float*)d_in[7];

  char* p = (char*)d_ws;
  const size_t ND2 = (size_t)NROWS * KDIM * 2;
  const size_t W2  = (size_t)KDIM * KDIM * 2;
  u16* xh = (u16*)p;  p += ND2;
  u16* xl = (u16*)p;  p += ND2;
  u16* fh = (u16*)p;  p += ND2;
  u16* fl = (u16*)p;  p += ND2;
  u16* gh = (u16*)p;  p += ND2;
  u16* gl = (u16*)p;  p += ND2;
  u16* vh = (u16*)p;  p += ND2;
  u16* wfh = (u16*)p; p += W2;
  u16* wfl = (u16*)p; p += W2;
  u16* wgh = (u16*)p; p += W2;
  u16* wgl = (u16*)p; p += W2;
  u16* wh  = (u16*)p; p += W2;
  u16* wl  = (u16*)p; p += W2;
  float* candS = (float*)p; p += (size_t)NROWS * CAP * 4;
  int*   candK = (int*)p;   p += (size_t)NROWS * CAP * 4;
  int*   cnts  = (int*)p;   p += (size_t)NROWS * 4;
  const size_t need = (size_t)(p - (char*)d_ws);
  if (ws_size < need) {
    ws_report<<<256, 256, 0, stream>>>((float*)d_out, (size_t)out_size, (float)ws_size);
    return;
  }
  // adjb (8 MB) aliases xl (16 MB): xl's last reader (pre-GEMMs) precedes
  // adjpack in stream order, and adjb's reader (scores) follows it.
  uint32_t* adjb = (uint32_t*)xl;

  auto kf = core_kernel<false, 3, true>;
  auto kv = core_kernel<false, 1, false>;
  auto ks = core_kernel<true, 3, false>;
  hipFuncSetAttribute((const void*)kf, hipFuncAttributeMaxDynamicSharedMemorySize, SM3);
  hipFuncSetAttribute((const void*)kv, hipFuncAttributeMaxDynamicSharedMemorySize, SM1);
  hipFuncSetAttribute((const void*)ks, hipFuncAttributeMaxDynamicSharedMemorySize, SM3);

  hipMemsetAsync(cnts, 0, (size_t)NROWS * 4, stream);
  wsplit_kernel<<<dim3(32, 32), 256, 0, stream>>>(Wf, wfh, wfl);
  wsplit_kernel<<<dim3(32, 32), 256, 0, stream>>>(Wg, wgh, wgl);
  wsplit_kernel<<<dim3(32, 32), 256, 0, stream>>>(W, wh, wl);
  xsplit_kernel<<<(NROWS * KDIM) / (256 * 4), 256, 0, stream>>>(x, xh, xl);

  // f = x@Wf + bf (split-3), g = x@Wg + bg (split-3), v = x@W + bW (1 pass)
  kf<<<dim3(256, 8), 512, SM3, stream>>>(xh, xl, wfh, wfl, bf_, fh, fl,
                                         nullptr, nullptr, nullptr, nullptr);
  kf<<<dim3(256, 8), 512, SM3, stream>>>(xh, xl, wgh, wgl, bg_, gh, gl,
                                         nullptr, nullptr, nullptr, nullptr);
  kv<<<dim3(256, 8), 512, SM1, stream>>>(xh, xl, wh, wl, bW_, vh, nullptr,
                                         nullptr, nullptr, nullptr, nullptr);
  // pack adjacency into bitmask (overwrites xl, no longer needed)
  adjpack_kernel<<<(NROWS * (NROWS / 32)) / 256, 256, 0, stream>>>(adj, adjb);
  // scores sweep: relu(f@g^T), mask, candidate emission
  ks<<<dim3(256, 1), 512, SM3, stream>>>(fh, fl, gh, gl, nullptr, nullptr, nullptr,
                                         adjb, candS, candK, cnts);
  // exact softmax over candidates + weighted gather of v rows
  finalize_kernel<<<NROWS, 256, 0, stream>>>(candS, candK, cnts, vh, (float*)d_out);
}

// Round 4
// 828.118 us; speedup vs baseline: 2.7184x; 1.9984x over previous
//
#include <hip/hip_runtime.h>
#include <stdint.h>

#define NROWS 8192
#define KDIM  1024
#define CAP   512
#define NEGBIG (-9.0e15f)
#define ADM_THR 20.0f

typedef __attribute__((ext_vector_type(8))) __bf16 bf16x8;
typedef __attribute__((ext_vector_type(4))) float f32x4;
typedef __attribute__((ext_vector_type(4))) unsigned short us4;
typedef __attribute__((ext_vector_type(4))) int i32x4;
typedef unsigned short u16;

__device__ __forceinline__ u16 f2bf(float f) {
  unsigned u = __float_as_uint(f);
  u += 0x7fffu + ((u >> 16) & 1u);
  return (u16)(u >> 16);
}
__device__ __forceinline__ float bf2f(u16 h) {
  return __uint_as_float(((unsigned)h) << 16);
}

__device__ __forceinline__ void glds16(const void* g, const char* lds) {
  __builtin_amdgcn_global_load_lds(
      (const __attribute__((address_space(1))) unsigned int*)(uintptr_t)g,
      (__attribute__((address_space(3))) unsigned int*)(uintptr_t)lds, 16, 0, 0);
}

__device__ __forceinline__ f32x4 mfma16(bf16x8 a, bf16x8 b, f32x4 c) {
  return __builtin_amdgcn_mfma_f32_16x16x32_bf16(a, b, c, 0, 0, 0);
}

// ---------------------------------------------------------------------------
// Tiled GEMM: C[128x128] tile = A[128xK] @ B[128xK]^T (A,B bf16 hi/lo).
// 8 waves (2M x 4N), wave out 64x32, BK=64, 2 LDS buffers, counted vmcnt.
// LDS per region: addr(row,kslot)=row*128+kslot*16 bytes; data swizzled
//   kcol_global = kslot ^ (row&7) (coalesced glds src + conflict-free reads).
// SCORES: persistent wg sweeps 16 key-tiles for one 128-row slab, carrying a
//   per-row running max across tiles + device atomicMax share across the 4
//   sibling wgs of the slab -> bounded candidate emission (superset of all
//   entries with true softmax weight > e^-ADM_THR of the row max).
// ---------------------------------------------------------------------------
template<int NSPLIT, bool SCORES, bool SPLITOUT>
__global__ __launch_bounds__(512, 1) void gemm_kernel(
    const u16* __restrict__ ah, const u16* __restrict__ al,
    const u16* __restrict__ bh, const u16* __restrict__ bl,
    const float* __restrict__ bias, u16* __restrict__ ch, u16* __restrict__ cl,
    const uint32_t* __restrict__ adjb, float* __restrict__ candS,
    int* __restrict__ candK, int* __restrict__ cnts, int* __restrict__ rowmax)
{
  extern __shared__ char smem[];
  constexpr int BUFS = (NSPLIT == 3) ? 65536 : 32768;
  constexpr int AHO = 0, ALO = 16384;
  constexpr int BHO = (NSPLIT == 3) ? 32768 : 16384;
  constexpr int BLO = 49152;
  constexpr int NT = KDIM / 64;

  const int tid = threadIdx.x, w = tid >> 6, lane = tid & 63;
  const int wr = w >> 2, wc = w & 3;

  int bx = 0, sub = 0;
  if constexpr (SCORES) {        // XCD x hosts slabs {x, x+8, ..}; 4 siblings/slab
    const int x = blockIdx.x & 7, y = blockIdx.x >> 3;
    bx = x + 8 * (y & 7);
    sub = y >> 3;                // sibling's by stride-offset, 0..3
  } else bx = blockIdx.x;

  const int arow0 = bx * 128;

  // ---- staging geometry: wave w stages rows [w*16, w*16+16); 8-lane groups
  //      read 128B contiguous (k-column permuted by row&7 = pre-swizzle).
  const int srow = w * 16 + (lane >> 3);
  const int scol = ((lane & 7) ^ (lane >> 3)) * 8;
  const size_t sgA = (size_t)(arow0 + srow) * KDIM + scol;
  const int ldsw = w * 2048;

  auto stg = [&](const u16* src, size_t sg, int kt, int ldsoff) {
    const u16* sp = src + sg + kt * 64;
    glds16(sp,            smem + ldsoff + ldsw);
    glds16(sp + 8 * KDIM, smem + ldsoff + ldsw + 1024);
  };

  // ---- fragment read offsets (swizzled k-slot)
  const int fa = (wr * 64 + (lane & 15)) * 128;
  const int fb = (wc * 32 + (lane & 15)) * 128;
  const int kqx0 = (((lane >> 4)    ) ^ (lane & 7)) * 16;
  const int kqx1 = (((lane >> 4) + 4) ^ (lane & 7)) * 16;

  const int l15 = lane & 15, g4 = (lane >> 4) << 2;
  float mrun[4][4];
  #pragma unroll
  for (int m = 0; m < 4; ++m)
    #pragma unroll
    for (int j = 0; j < 4; ++j) mrun[m][j] = NEGBIG;

  const int NITER = SCORES ? (NROWS / 128 / 4) : 1;

  for (int it = 0; it < NITER; ++it) {
    const int by = SCORES ? (sub + 4 * it) : blockIdx.y;
    const int bcol0 = by * 128;
    const size_t sgB = (size_t)(bcol0 + srow) * KDIM + scol;

    // ---- prologue: establish 8 glds in flight
    stg(ah, sgA, 0, AHO); stg(bh, sgB, 0, BHO);
    if constexpr (NSPLIT == 3) { stg(al, sgA, 0, ALO); stg(bl, sgB, 0, BLO); }
    else { stg(ah, sgA, 1, AHO + BUFS); stg(bh, sgB, 1, BHO + BUFS); }

    f32x4 acc[4][2];
    #pragma unroll
    for (int m = 0; m < 4; ++m) {
      acc[m][0] = f32x4{0.f, 0.f, 0.f, 0.f};
      acc[m][1] = f32x4{0.f, 0.f, 0.f, 0.f};
    }

    for (int t = 0; t < NT; ++t) {
      const int bo  = (t & 1) * BUFS;
      const int bo2 = ((t + 1) & 1) * BUFS;

      // ---- phase A: hi halves of buf t ready past this wait+barrier
      if (NSPLIT == 1 && t == NT - 1) asm volatile("s_waitcnt vmcnt(0)" ::: "memory");
      else                            asm volatile("s_waitcnt vmcnt(4)" ::: "memory");
      __builtin_amdgcn_s_barrier();
      __builtin_amdgcn_sched_barrier(0);

      if (NSPLIT == 3 && t + 1 < NT) {
        stg(ah, sgA, t + 1, AHO + bo2);
        stg(bh, sgB, t + 1, BHO + bo2);
      }

      bf16x8 a0[4][2], b0[2][2];
      #pragma unroll
      for (int m = 0; m < 4; ++m) {
        a0[m][0] = *(const bf16x8*)(smem + AHO + bo + fa + m * 2048 + kqx0);
        a0[m][1] = *(const bf16x8*)(smem + AHO + bo + fa + m * 2048 + kqx1);
      }
      #pragma unroll
      for (int n = 0; n < 2; ++n) {
        b0[n][0] = *(const bf16x8*)(smem + BHO + bo + fb + n * 2048 + kqx0);
        b0[n][1] = *(const bf16x8*)(smem + BHO + bo + fb + n * 2048 + kqx1);
      }
      __builtin_amdgcn_s_setprio(1);
      #pragma unroll
      for (int kq = 0; kq < 2; ++kq)
        #pragma unroll
        for (int m = 0; m < 4; ++m)
          #pragma unroll
          for (int n = 0; n < 2; ++n)
            acc[m][n] = mfma16(a0[m][kq], b0[n][kq], acc[m][n]);
      __builtin_amdgcn_s_setprio(0);
      // drain own ds_reads before any wave can pass the next barrier and
      // overwrite the region (WAR airtight regardless of MFMA scheduling)
      asm volatile("s_waitcnt lgkmcnt(0)" ::: "memory");

      if constexpr (NSPLIT == 3) {
        // ---- phase B: lo halves of buf t ready
        if (t + 1 < NT) asm volatile("s_waitcnt vmcnt(4)" ::: "memory");
        else            asm volatile("s_waitcnt vmcnt(0)" ::: "memory");
        __builtin_amdgcn_s_barrier();
        __builtin_amdgcn_sched_barrier(0);

        if (t + 1 < NT) {
          stg(al, sgA, t + 1, ALO + bo2);
          stg(bl, sgB, t + 1, BLO + bo2);
        }
        bf16x8 a1[4][2], b1[2][2];
        #pragma unroll
        for (int m = 0; m < 4; ++m) {
          a1[m][0] = *(const bf16x8*)(smem + ALO + bo + fa + m * 2048 + kqx0);
          a1[m][1] = *(const bf16x8*)(smem + ALO + bo + fa + m * 2048 + kqx1);
        }
        #pragma unroll
        for (int n = 0; n < 2; ++n) {
          b1[n][0] = *(const bf16x8*)(smem + BLO + bo + fb + n * 2048 + kqx0);
          b1[n][1] = *(const bf16x8*)(smem + BLO + bo + fb + n * 2048 + kqx1);
        }
        __builtin_amdgcn_s_setprio(1);
        #pragma unroll
        for (int kq = 0; kq < 2; ++kq)
          #pragma unroll
          for (int m = 0; m < 4; ++m)
            #pragma unroll
            for (int n = 0; n < 2; ++n)
              acc[m][n] = mfma16(a1[m][kq], b0[n][kq], acc[m][n]);
        #pragma unroll
        for (int kq = 0; kq < 2; ++kq)
          #pragma unroll
          for (int m = 0; m < 4; ++m)
            #pragma unroll
            for (int n = 0; n < 2; ++n)
              acc[m][n] = mfma16(a0[m][kq], b1[n][kq], acc[m][n]);
        __builtin_amdgcn_s_setprio(0);
        asm volatile("s_waitcnt lgkmcnt(0)" ::: "memory");
      } else {
        // all waves done reading buf t -> safe to overwrite with tile t+2
        __builtin_amdgcn_s_barrier();
        if (t + 2 < NT) {
          stg(ah, sgA, t + 2, AHO + bo);
          stg(bh, sgB, t + 2, BHO + bo);
        }
      }
    }

    if constexpr (SCORES) {
      const unsigned long long lmask = (1ull << lane) - 1ull;
      const unsigned long long gm = 0xFFFFull << (lane & 48);
      const int k0 = bcol0 + wc * 32 + l15;
      #pragma unroll
      for (int m = 0; m < 4; ++m) {
        #pragma unroll
        for (int j = 0; j < 4; ++j) {
          const int row = arow0 + wr * 64 + m * 16 + g4 + j;
          const uint32_t awd = adjb[(size_t)row * (NROWS / 32) + (bcol0 >> 5) + wc];
          float v0 = fmaxf(acc[m][0][j], 0.f);                 // relu
          float v1 = fmaxf(acc[m][1][j], 0.f);
          float s0v = ((awd >> l15) & 1u) ? v0 : NEGBIG;       // adjacency mask
          float s1v = ((awd >> (l15 + 16)) & 1u) ? v1 : NEGBIG;
          float rm = fmaxf(s0v, s1v);                          // 32-key group max
          rm = fmaxf(rm, __shfl_xor(rm, 1));
          rm = fmaxf(rm, __shfl_xor(rm, 2));
          rm = fmaxf(rm, __shfl_xor(rm, 4));
          rm = fmaxf(rm, __shfl_xor(rm, 8));
          float mr = fmaxf(mrun[m][j], rm);                    // running across tiles
          int old = 0;                                         // share across siblings
          if (l15 == 0) old = atomicMax(rowmax + row, __float_as_int(mr));
          old = __shfl(old, lane & 48);
          mr = fmaxf(mr, __int_as_float(old));
          mrun[m][j] = mr;
          const float thr = mr - ADM_THR;
          bool e0 = s0v > thr, e1 = s1v > thr;
          unsigned long long m0 = __ballot(e0), m1 = __ballot(e1);
          int n0 = __popcll(m0 & gm), n1 = __popcll(m1 & gm);
          int base = 0;
          if (l15 == 0 && (n0 + n1) > 0) base = atomicAdd(cnts + row, n0 + n1);
          base = __shfl(base, lane & 48);
          int p0 = base + __popcll(m0 & gm & lmask);
          int p1 = base + n0 + __popcll(m1 & gm & lmask);
          if (e0 && p0 < CAP) { candS[(size_t)row * CAP + p0] = s0v;
                                candK[(size_t)row * CAP + p0] = k0; }
          if (e1 && p1 < CAP) { candS[(size_t)row * CAP + p1] = s1v;
                                candK[(size_t)row * CAP + p1] = k0 + 16; }
        }
      }
    } else {
      const int colb = bcol0 + wc * 32 + l15;
      const float bi0 = bias[colb], bi1 = bias[colb + 16];
      #pragma unroll
      for (int m = 0; m < 4; ++m) {
        #pragma unroll
        for (int j = 0; j < 4; ++j) {
          const int row = arow0 + wr * 64 + m * 16 + g4 + j;
          float v0 = acc[m][0][j] + bi0, v1 = acc[m][1][j] + bi1;
          u16 h0 = f2bf(v0), h1 = f2bf(v1);
          ch[(size_t)row * KDIM + colb] = h0;
          ch[(size_t)row * KDIM + colb + 16] = h1;
          if constexpr (SPLITOUT) {
            cl[(size_t)row * KDIM + colb] = f2bf(v0 - bf2f(h0));
            cl[(size_t)row * KDIM + colb + 16] = f2bf(v1 - bf2f(h1));
          }
        }
      }
    }
  }
}

// ---------------------------------------------------------------------------
// adj (int32 0/1, 268 MB) -> bitmask (8 MB). BW-bound single pass.
// ---------------------------------------------------------------------------
__global__ __launch_bounds__(256) void adjpack_kernel(
    const int* __restrict__ adj, uint32_t* __restrict__ adjb)
{
  size_t w = (size_t)blockIdx.x * 256 + threadIdx.x;
  const int* src = adj + (w << 5);
  uint32_t m = 0;
  #pragma unroll
  for (int j = 0; j < 8; ++j) {
    i32x4 v = *(const i32x4*)(src + j * 4);
    m |= (v[0] > 0 ? 1u : 0u) << (j * 4)
       | (v[1] > 0 ? 1u : 0u) << (j * 4 + 1)
       | (v[2] > 0 ? 1u : 0u) << (j * 4 + 2)
       | (v[3] > 0 ? 1u : 0u) << (j * 4 + 3);
  }
  adjb[w] = m;
}

// ---------------------------------------------------------------------------
// Exact softmax over candidates; prune weights < 2e-8, weighted gather of v.
// ---------------------------------------------------------------------------
__global__ __launch_bounds__(256) void finalize_kernel(
    const float* __restrict__ candS, const int* __restrict__ candK,
    const int* __restrict__ cnts, const u16* __restrict__ vh,
    float* __restrict__ out)
{
  const int row = blockIdx.x, tid = threadIdx.x;
  __shared__ float sS[CAP];
  __shared__ int sK[CAP];
  __shared__ float sW2[CAP];
  __shared__ int sK2[CAP];
  __shared__ float red[4];
  __shared__ int nsig;
  int cnt = cnts[row]; cnt = cnt < CAP ? cnt : CAP;
  const int col = tid * 4;
  if (cnt <= 0) {
    f32x4 z = {0.f, 0.f, 0.f, 0.f};
    *(f32x4*)(out + (size_t)row * KDIM + col) = z;
    return;
  }
  if (tid == 0) nsig = 0;
  for (int i = tid; i < cnt; i += 256) {
    sS[i] = candS[(size_t)row * CAP + i];
    sK[i] = candK[(size_t)row * CAP + i];
  }
  __syncthreads();
  float lm = NEGBIG;
  for (int i = tid; i < cnt; i += 256) lm = fmaxf(lm, sS[i]);
  #pragma unroll
  for (int d = 1; d < 64; d <<= 1) lm = fmaxf(lm, __shfl_xor(lm, d));
  if ((tid & 63) == 0) red[tid >> 6] = lm;
  __syncthreads();
  const float m = fmaxf(fmaxf(red[0], red[1]), fmaxf(red[2], red[3]));
  __syncthreads();
  float ls = 0.f;
  for (int i = tid; i < cnt; i += 256) {
    float wv = __expf(sS[i] - m);
    ls += wv;
    if (wv > 2e-8f) {
      int p = atomicAdd(&nsig, 1);
      sW2[p] = wv; sK2[p] = sK[i];
    }
  }
  #pragma unroll
  for (int d = 1; d < 64; d <<= 1) ls += __shfl_xor(ls, d);
  if ((tid & 63) == 0) red[tid >> 6] = ls;
  __syncthreads();
  const float inv = 1.f / (red[0] + red[1] + red[2] + red[3]);
  const int ns = nsig;
  float a0 = 0.f, a1 = 0.f, a2 = 0.f, a3 = 0.f;
  const u16* vbase = vh + col;
  for (int i = 0; i < ns; ++i) {
    float wv = sW2[i];
    us4 vv = *(const us4*)(vbase + (size_t)sK2[i] * KDIM);
    a0 += wv * bf2f(vv[0]); a1 += wv * bf2f(vv[1]);
    a2 += wv * bf2f(vv[2]); a3 += wv * bf2f(vv[3]);
  }
  f32x4 o = {a0 * inv, a1 * inv, a2 * inv, a3 * inv};
  *(f32x4*)(out + (size_t)row * KDIM + col) = o;
}

// ---------------------------------------------------------------------------
// Transpose + hi/lo split of a [K][N] fp32 weight into [N][K] bf16 pair.
// ---------------------------------------------------------------------------
__global__ __launch_bounds__(256) void wsplit_kernel(
    const float* __restrict__ W, u16* __restrict__ th, u16* __restrict__ tl)
{
  __shared__ float tile[32][33];
  const int bx = blockIdx.x, by = blockIdx.y;
  const int tx = threadIdx.x & 31, ty = threadIdx.x >> 5;
  #pragma unroll
  for (int i = 0; i < 4; ++i) {
    int ky = ty + i * 8;
    tile[ky][tx] = W[(size_t)(by * 32 + ky) * KDIM + bx * 32 + tx];
  }
  __syncthreads();
  #pragma unroll
  for (int i = 0; i < 4; ++i) {
    int ny = ty + i * 8;
    float v = tile[tx][ny];
    u16 h = f2bf(v);
    th[(size_t)(bx * 32 + ny) * KDIM + by * 32 + tx] = h;
    tl[(size_t)(bx * 32 + ny) * KDIM + by * 32 + tx] = f2bf(v - bf2f(h));
  }
}

__global__ __launch_bounds__(256) void xsplit_kernel(
    const float* __restrict__ x, u16* __restrict__ xh, u16* __restrict__ xl)
{
  size_t i = ((size_t)blockIdx.x * 256 + threadIdx.x) * 4;
  f32x4 v = *(const f32x4*)(x + i);
  us4 h, l;
  #pragma unroll
  for (int j = 0; j < 4; ++j) {
    h[j] = f2bf(v[j]);
    l[j] = f2bf(v[j] - bf2f(h[j]));
  }
  *(us4*)(xh + i) = h;
  *(us4*)(xl + i) = l;
}

__global__ void ws_report(float* out, size_t n, float v) {
  for (size_t i = (size_t)blockIdx.x * blockDim.x + threadIdx.x; i < n;
       i += (size_t)gridDim.x * blockDim.x) out[i] = v;
}

extern "C" void kernel_launch(void* const* d_in, const int* in_sizes, int n_in,
                              void* d_out, int out_size, void* d_ws, size_t ws_size,
                              hipStream_t stream) {
  (void)in_sizes; (void)n_in;
  const float* x   = (const float*)d_in[0];
  const int*   adj = (const int*)d_in[1];
  const float* Wf  = (const float*)d_in[2];
  const float* bf_ = (const float*)d_in[3];
  const float* Wg  = (const float*)d_in[4];
  const float* bg_ = (const float*)d_in[5];
  const float* W   = (const float*)d_in[6];
  const float* bW_ = (const float*)d_in[7];

  char* p = (char*)d_ws;
  const size_t ND2 = (size_t)NROWS * KDIM * 2;
  const size_t W2  = (size_t)KDIM * KDIM * 2;
  u16* xh = (u16*)p;  p += ND2;
  u16* xl = (u16*)p;  p += ND2;
  u16* fh = (u16*)p;  p += ND2;
  u16* fl = (u16*)p;  p += ND2;
  u16* gh = (u16*)p;  p += ND2;
  u16* gl = (u16*)p;  p += ND2;
  u16* vh = (u16*)p;  p += ND2;
  u16* wfh = (u16*)p; p += W2;
  u16* wfl = (u16*)p; p += W2;
  u16* wgh = (u16*)p; p += W2;
  u16* wgl = (u16*)p; p += W2;
  u16* wh  = (u16*)p; p += W2;
  u16* wl  = (u16*)p; p += W2;
  float* candS = (float*)p; p += (size_t)NROWS * CAP * 4;
  int*   candK = (int*)p;   p += (size_t)NROWS * CAP * 4;
  int*   cnts  = (int*)p;   p += (size_t)NROWS * 4;
  int*   rowmax= (int*)p;   p += (size_t)NROWS * 4;
  const size_t need = (size_t)(p - (char*)d_ws);
  if (ws_size < need) {
    ws_report<<<256, 256, 0, stream>>>((float*)d_out, (size_t)out_size, (float)ws_size);
    return;
  }
  uint32_t* adjb = (uint32_t*)xl;   // aliases xl after pre-GEMMs are done

  auto kf = gemm_kernel<3, false, true>;
  auto kv = gemm_kernel<1, false, false>;
  auto ks = gemm_kernel<3, true, false>;
  hipFuncSetAttribute((const void*)kf, hipFuncAttributeMaxDynamicSharedMemorySize, 131072);
  hipFuncSetAttribute((const void*)kv, hipFuncAttributeMaxDynamicSharedMemorySize, 65536);
  hipFuncSetAttribute((const void*)ks, hipFuncAttributeMaxDynamicSharedMemorySize, 131072);

  hipMemsetAsync(cnts, 0, (size_t)NROWS * 8, stream);   // cnts + rowmax (0 == 0.0f)
  wsplit_kernel<<<dim3(32, 32), 256, 0, stream>>>(Wf, wfh, wfl);
  wsplit_kernel<<<dim3(32, 32), 256, 0, stream>>>(Wg, wgh, wgl);
  wsplit_kernel<<<dim3(32, 32), 256, 0, stream>>>(W, wh, wl);
  xsplit_kernel<<<(NROWS * KDIM) / (256 * 4), 256, 0, stream>>>(x, xh, xl);

  // f = x@Wf + bf, g = x@Wg + bg (split-3), v = x@W + bW (1 pass)
  kf<<<dim3(64, 8), 512, 131072, stream>>>(xh, xl, wfh, wfl, bf_, fh, fl,
                                           nullptr, nullptr, nullptr, nullptr, nullptr);
  kf<<<dim3(64, 8), 512, 131072, stream>>>(xh, xl, wgh, wgl, bg_, gh, gl,
                                           nullptr, nullptr, nullptr, nullptr, nullptr);
  kv<<<dim3(64, 8), 512, 65536, stream>>>(xh, xl, wh, wl, bW_, vh, nullptr,
                                          nullptr, nullptr, nullptr, nullptr, nullptr);
  adjpack_kernel<<<(NROWS * (NROWS / 32)) / 256, 256, 0, stream>>>(adj, adjb);
  // scores: persistent wgs, relu(f@g^T), mask, bounded candidate emission
  ks<<<dim3(256), 512, 131072, stream>>>(fh, fl, gh, gl, nullptr, nullptr, nullptr,
                                         adjb, candS, candK, cnts, rowmax);
  finalize_kernel<<<NROWS, 256, 0, stream>>>(candS, candK, cnts, vh, (float*)d_out);
}

// Round 5
// 627.839 us; speedup vs baseline: 3.5855x; 1.3190x over previous
//
#include <hip/hip_runtime.h>
#include <stdint.h>

#define NROWS 8192
#define KDIM  1024
#define CAP   512
#define NEGBIG (-9.0e15f)
#define EMIT_THR 16.0f
#define SURV_THR 13.5f
#define MAXS  128

typedef __attribute__((ext_vector_type(8))) __bf16 bf16x8;
typedef __attribute__((ext_vector_type(4))) float f32x4;
typedef __attribute__((ext_vector_type(4))) unsigned short us4;
typedef __attribute__((ext_vector_type(4))) int i32x4;
typedef unsigned short u16;

__device__ __forceinline__ u16 f2bf(float f) {
  unsigned u = __float_as_uint(f);
  u += 0x7fffu + ((u >> 16) & 1u);
  return (u16)(u >> 16);
}
__device__ __forceinline__ float bf2f(u16 h) {
  return __uint_as_float(((unsigned)h) << 16);
}

__device__ __forceinline__ void glds16(const void* g, const char* lds) {
  __builtin_amdgcn_global_load_lds(
      (const __attribute__((address_space(1))) unsigned int*)(uintptr_t)g,
      (__attribute__((address_space(3))) unsigned int*)(uintptr_t)lds, 16, 0, 0);
}

__device__ __forceinline__ f32x4 mfma16(bf16x8 a, bf16x8 b, f32x4 c) {
  return __builtin_amdgcn_mfma_f32_16x16x32_bf16(a, b, c, 0, 0, 0);
}

// ---------------------------------------------------------------------------
// Pre-GEMM (R4-proven): C[128x128] = A@B^T, split-3 (NSPLIT=3) or 1-pass.
// Writes bf16-hi C, and bf16-lo C when SPLITOUT (f,g keep full precision as
// an hi+lo pair for exact rescoring in finalize).
// ---------------------------------------------------------------------------
template<int NSPLIT, bool SPLITOUT>
__global__ __launch_bounds__(512, 1) void gemm_kernel(
    const u16* __restrict__ ah, const u16* __restrict__ al,
    const u16* __restrict__ bh, const u16* __restrict__ bl,
    const float* __restrict__ bias, u16* __restrict__ ch, u16* __restrict__ cl)
{
  extern __shared__ char smem[];
  constexpr int BUFS = (NSPLIT == 3) ? 65536 : 32768;
  constexpr int AHO = 0, ALO = 16384;
  constexpr int BHO = (NSPLIT == 3) ? 32768 : 16384;
  constexpr int BLO = 49152;
  constexpr int NT = KDIM / 64;

  const int tid = threadIdx.x, w = tid >> 6, lane = tid & 63;
  const int wr = w >> 2, wc = w & 3;
  const int bx = blockIdx.x, by = blockIdx.y;
  const int arow0 = bx * 128, bcol0 = by * 128;

  const int srow = w * 16 + (lane >> 3);
  const int scol = ((lane & 7) ^ (lane >> 3)) * 8;
  const size_t sgA = (size_t)(arow0 + srow) * KDIM + scol;
  const size_t sgB = (size_t)(bcol0 + srow) * KDIM + scol;
  const int ldsw = w * 2048;

  auto stg = [&](const u16* src, size_t sg, int kt, int ldsoff) {
    const u16* sp = src + sg + kt * 64;
    glds16(sp,            smem + ldsoff + ldsw);
    glds16(sp + 8 * KDIM, smem + ldsoff + ldsw + 1024);
  };

  const int fa = (wr * 64 + (lane & 15)) * 128;
  const int fb = (wc * 32 + (lane & 15)) * 128;
  const int kqx0 = (((lane >> 4)    ) ^ (lane & 7)) * 16;
  const int kqx1 = (((lane >> 4) + 4) ^ (lane & 7)) * 16;

  stg(ah, sgA, 0, AHO); stg(bh, sgB, 0, BHO);
  if constexpr (NSPLIT == 3) { stg(al, sgA, 0, ALO); stg(bl, sgB, 0, BLO); }
  else { stg(ah, sgA, 1, AHO + BUFS); stg(bh, sgB, 1, BHO + BUFS); }

  f32x4 acc[4][2];
  #pragma unroll
  for (int m = 0; m < 4; ++m) {
    acc[m][0] = f32x4{0.f, 0.f, 0.f, 0.f};
    acc[m][1] = f32x4{0.f, 0.f, 0.f, 0.f};
  }

  for (int t = 0; t < NT; ++t) {
    const int bo  = (t & 1) * BUFS;
    const int bo2 = ((t + 1) & 1) * BUFS;

    if (NSPLIT == 1 && t == NT - 1) asm volatile("s_waitcnt vmcnt(0)" ::: "memory");
    else                            asm volatile("s_waitcnt vmcnt(4)" ::: "memory");
    __builtin_amdgcn_s_barrier();
    __builtin_amdgcn_sched_barrier(0);

    if (NSPLIT == 3 && t + 1 < NT) {
      stg(ah, sgA, t + 1, AHO + bo2);
      stg(bh, sgB, t + 1, BHO + bo2);
    }

    bf16x8 a0[4][2], b0[2][2];
    #pragma unroll
    for (int m = 0; m < 4; ++m) {
      a0[m][0] = *(const bf16x8*)(smem + AHO + bo + fa + m * 2048 + kqx0);
      a0[m][1] = *(const bf16x8*)(smem + AHO + bo + fa + m * 2048 + kqx1);
    }
    #pragma unroll
    for (int n = 0; n < 2; ++n) {
      b0[n][0] = *(const bf16x8*)(smem + BHO + bo + fb + n * 2048 + kqx0);
      b0[n][1] = *(const bf16x8*)(smem + BHO + bo + fb + n * 2048 + kqx1);
    }
    __builtin_amdgcn_s_setprio(1);
    #pragma unroll
    for (int kq = 0; kq < 2; ++kq)
      #pragma unroll
      for (int m = 0; m < 4; ++m)
        #pragma unroll
        for (int n = 0; n < 2; ++n)
          acc[m][n] = mfma16(a0[m][kq], b0[n][kq], acc[m][n]);
    __builtin_amdgcn_s_setprio(0);
    asm volatile("s_waitcnt lgkmcnt(0)" ::: "memory");

    if constexpr (NSPLIT == 3) {
      if (t + 1 < NT) asm volatile("s_waitcnt vmcnt(4)" ::: "memory");
      else            asm volatile("s_waitcnt vmcnt(0)" ::: "memory");
      __builtin_amdgcn_s_barrier();
      __builtin_amdgcn_sched_barrier(0);

      if (t + 1 < NT) {
        stg(al, sgA, t + 1, ALO + bo2);
        stg(bl, sgB, t + 1, BLO + bo2);
      }
      bf16x8 a1[4][2], b1[2][2];
      #pragma unroll
      for (int m = 0; m < 4; ++m) {
        a1[m][0] = *(const bf16x8*)(smem + ALO + bo + fa + m * 2048 + kqx0);
        a1[m][1] = *(const bf16x8*)(smem + ALO + bo + fa + m * 2048 + kqx1);
      }
      #pragma unroll
      for (int n = 0; n < 2; ++n) {
        b1[n][0] = *(const bf16x8*)(smem + BLO + bo + fb + n * 2048 + kqx0);
        b1[n][1] = *(const bf16x8*)(smem + BLO + bo + fb + n * 2048 + kqx1);
      }
      __builtin_amdgcn_s_setprio(1);
      #pragma unroll
      for (int kq = 0; kq < 2; ++kq)
        #pragma unroll
        for (int m = 0; m < 4; ++m)
          #pragma unroll
          for (int n = 0; n < 2; ++n)
            acc[m][n] = mfma16(a1[m][kq], b0[n][kq], acc[m][n]);
      #pragma unroll
      for (int kq = 0; kq < 2; ++kq)
        #pragma unroll
        for (int m = 0; m < 4; ++m)
          #pragma unroll
          for (int n = 0; n < 2; ++n)
            acc[m][n] = mfma16(a0[m][kq], b1[n][kq], acc[m][n]);
      __builtin_amdgcn_s_setprio(0);
      asm volatile("s_waitcnt lgkmcnt(0)" ::: "memory");
    } else {
      __builtin_amdgcn_s_barrier();
      if (t + 2 < NT) {
        stg(ah, sgA, t + 2, AHO + bo);
        stg(bh, sgB, t + 2, BHO + bo);
      }
    }
  }

  const int l15 = lane & 15, g4 = (lane >> 4) << 2;
  const int colb = bcol0 + wc * 32 + l15;
  const float bi0 = bias[colb], bi1 = bias[colb + 16];
  #pragma unroll
  for (int m = 0; m < 4; ++m) {
    #pragma unroll
    for (int j = 0; j < 4; ++j) {
      const int row = arow0 + wr * 64 + m * 16 + g4 + j;
      float v0 = acc[m][0][j] + bi0, v1 = acc[m][1][j] + bi1;
      u16 h0 = f2bf(v0), h1 = f2bf(v1);
      ch[(size_t)row * KDIM + colb] = h0;
      ch[(size_t)row * KDIM + colb + 16] = h1;
      if constexpr (SPLITOUT) {
        cl[(size_t)row * KDIM + colb] = f2bf(v0 - bf2f(h0));
        cl[(size_t)row * KDIM + colb + 16] = f2bf(v1 - bf2f(h1));
      }
    }
  }
}

// ---------------------------------------------------------------------------
// Scores sweep, single-pass bf16: relu(fh@gh^T), adjacency mask, running-max
// candidate emission packed (key | bf16(score)<<16). 512 persistent wgs
// (2/CU), each owns a 128-row slab and sweeps 8 of the 64 key-tiles; flat
// 128-K-tile loop so prefetch flows through epilogues. Counted vmcnt(4)
// (oldest-retire-first, m135); one vmcnt(0) drain per key-tile epilogue keeps
// the count clean around emission stores/atomics.
// ---------------------------------------------------------------------------
__global__ __launch_bounds__(512, 4) void scores_kernel(
    const u16* __restrict__ fh, const u16* __restrict__ gh,
    const uint32_t* __restrict__ adjb, uint32_t* __restrict__ cand,
    int* __restrict__ cnts, int* __restrict__ rowmax)
{
  extern __shared__ char smem[];
  constexpr int BUFS = 32768, AHO = 0, BHO = 16384;
  constexpr int NTT = 16;           // K-tiles per key-tile
  constexpr int NSUB = 8;           // siblings per 128-row slab
  constexpr int NIT = 64 / NSUB;    // key-tiles per wg
  constexpr int KT = NIT * NTT;     // 128 flat K-tiles

  const int tid = threadIdx.x, w = tid >> 6, lane = tid & 63;
  const int wr = w >> 2, wc = w & 3;
  const int l15 = lane & 15, g4 = (lane >> 4) << 2;

  const int xcd = blockIdx.x & 7, idx = blockIdx.x >> 3;
  const int bx  = xcd * 8 + (idx & 7);
  const int sub = idx >> 3;
  const int arow0 = bx * 128;

  const int srow = w * 16 + (lane >> 3);
  const int scol = ((lane & 7) ^ (lane >> 3)) * 8;
  const size_t sgA = (size_t)(arow0 + srow) * KDIM + scol;
  const int ldsw = w * 2048;

  auto stage = [&](int kt) {
    const int it = kt >> 4, t = kt & 15;
    const int bo = (kt & 1) * BUFS;
    const int by = sub + NSUB * it;
    const u16* pa = fh + sgA + t * 64;
    const u16* pb = gh + (size_t)(by * 128 + srow) * KDIM + scol + t * 64;
    glds16(pa,            smem + AHO + bo + ldsw);
    glds16(pa + 8 * KDIM, smem + AHO + bo + ldsw + 1024);
    glds16(pb,            smem + BHO + bo + ldsw);
    glds16(pb + 8 * KDIM, smem + BHO + bo + ldsw + 1024);
  };

  const int fa = (wr * 64 + l15) * 128;
  const int fb = (wc * 32 + l15) * 128;
  const int kqx0 = (((lane >> 4)    ) ^ (lane & 7)) * 16;
  const int kqx1 = (((lane >> 4) + 4) ^ (lane & 7)) * 16;

  float mrun[4][4];
  uint32_t awc[4][4];
  #pragma unroll
  for (int m = 0; m < 4; ++m)
    #pragma unroll
    for (int j = 0; j < 4; ++j) {
      const int row = arow0 + wr * 64 + m * 16 + g4 + j;
      awc[m][j] = adjb[(size_t)row * (NROWS / 32) + sub * 4 + wc];
      mrun[m][j] = fmaxf(NEGBIG, __int_as_float(rowmax[row]));
    }
  asm volatile("s_waitcnt vmcnt(0)" ::: "memory");  // clean count before loop
  stage(0); stage(1);

  f32x4 acc[4][2];
  #pragma unroll
  for (int m = 0; m < 4; ++m) {
    acc[m][0] = f32x4{0.f, 0.f, 0.f, 0.f};
    acc[m][1] = f32x4{0.f, 0.f, 0.f, 0.f};
  }

  const unsigned long long lmask = (1ull << lane) - 1ull;
  const unsigned long long gm = 0xFFFFull << (lane & 48);

  for (int kt = 0; kt < KT; ++kt) {
    const int bo = (kt & 1) * BUFS;

    if (kt == KT - 1) asm volatile("s_waitcnt vmcnt(0)" ::: "memory");
    else              asm volatile("s_waitcnt vmcnt(4)" ::: "memory");
    __builtin_amdgcn_s_barrier();
    __builtin_amdgcn_sched_barrier(0);

    bf16x8 a0[4][2], b0[2][2];
    #pragma unroll
    for (int m = 0; m < 4; ++m) {
      a0[m][0] = *(const bf16x8*)(smem + AHO + bo + fa + m * 2048 + kqx0);
      a0[m][1] = *(const bf16x8*)(smem + AHO + bo + fa + m * 2048 + kqx1);
    }
    #pragma unroll
    for (int n = 0; n < 2; ++n) {
      b0[n][0] = *(const bf16x8*)(smem + BHO + bo + fb + n * 2048 + kqx0);
      b0[n][1] = *(const bf16x8*)(smem + BHO + bo + fb + n * 2048 + kqx1);
    }
    __builtin_amdgcn_s_setprio(1);
    #pragma unroll
    for (int kq = 0; kq < 2; ++kq)
      #pragma unroll
      for (int m = 0; m < 4; ++m)
        #pragma unroll
        for (int n = 0; n < 2; ++n)
          acc[m][n] = mfma16(a0[m][kq], b0[n][kq], acc[m][n]);
    __builtin_amdgcn_s_setprio(0);
    asm volatile("s_waitcnt lgkmcnt(0)" ::: "memory");
    __builtin_amdgcn_s_barrier();

    if (kt + 2 < KT) stage(kt + 2);

    if ((kt & 15) == 15) {
      const int it = kt >> 4;
      const int bcol0 = (sub + NSUB * it) * 128;
      const int k0 = bcol0 + wc * 32 + l15;
      #pragma unroll
      for (int m = 0; m < 4; ++m) {
        #pragma unroll
        for (int j = 0; j < 4; ++j) {
          const int row = arow0 + wr * 64 + m * 16 + g4 + j;
          float v0 = fmaxf(acc[m][0][j], 0.f);
          float v1 = fmaxf(acc[m][1][j], 0.f);
          float s0v = ((awc[m][j] >> l15) & 1u) ? v0 : NEGBIG;
          float s1v = ((awc[m][j] >> (l15 + 16)) & 1u) ? v1 : NEGBIG;
          float rm = fmaxf(s0v, s1v);
          rm = fmaxf(rm, __shfl_xor(rm, 1));
          rm = fmaxf(rm, __shfl_xor(rm, 2));
          rm = fmaxf(rm, __shfl_xor(rm, 4));
          rm = fmaxf(rm, __shfl_xor(rm, 8));
          const float mr = fmaxf(mrun[m][j], rm);
          mrun[m][j] = mr;
          if (l15 == 0 && rm >= mr) atomicMax(rowmax + row, __float_as_int(mr));
          const float thr = mr - EMIT_THR;
          bool e0 = s0v > thr, e1 = s1v > thr;
          unsigned long long m0 = __ballot(e0), m1 = __ballot(e1);
          int n0 = __popcll(m0 & gm), n1 = __popcll(m1 & gm);
          int base = 0;
          if (l15 == 0 && (n0 + n1) > 0) base = atomicAdd(cnts + row, n0 + n1);
          base = __shfl(base, lane & 48);
          int p0 = base + __popcll(m0 & gm & lmask);
          int p1 = base + n0 + __popcll(m1 & gm & lmask);
          if (e0 && p0 < CAP)
            cand[(size_t)row * CAP + p0] = ((uint32_t)f2bf(s0v) << 16) | (uint32_t)k0;
          if (e1 && p1 < CAP)
            cand[(size_t)row * CAP + p1] = ((uint32_t)f2bf(s1v) << 16) | (uint32_t)(k0 + 16);
          acc[m][0][j] = 0.f; acc[m][1][j] = 0.f;
        }
      }
      if (it + 1 < NIT) {
        uint32_t awn[4][4]; float rmn[4][4];
        #pragma unroll
        for (int m = 0; m < 4; ++m)
          #pragma unroll
          for (int j = 0; j < 4; ++j) {
            const int row = arow0 + wr * 64 + m * 16 + g4 + j;
            awn[m][j] = adjb[(size_t)row * (NROWS / 32) + (sub + NSUB * (it + 1)) * 4 + wc];
            rmn[m][j] = __int_as_float(rowmax[row]);   // stale-tolerant share
          }
        asm volatile("s_waitcnt vmcnt(0)" ::: "memory"); // drain: clean count resumes
        #pragma unroll
        for (int m = 0; m < 4; ++m)
          #pragma unroll
          for (int j = 0; j < 4; ++j) {
            awc[m][j] = awn[m][j];
            mrun[m][j] = fmaxf(mrun[m][j], rmn[m][j]);
          }
      }
    }
  }
}

// ---------------------------------------------------------------------------
// adj (int32 0/1, 268 MB) -> bitmask (8 MB). BW-bound single pass.
// ---------------------------------------------------------------------------
__global__ __launch_bounds__(256) void adjpack_kernel(
    const int* __restrict__ adj, uint32_t* __restrict__ adjb)
{
  size_t w = (size_t)blockIdx.x * 256 + threadIdx.x;
  const int* src = adj + (w << 5);
  uint32_t m = 0;
  #pragma unroll
  for (int j = 0; j < 8; ++j) {
    i32x4 v = *(const i32x4*)(src + j * 4);
    m |= (v[0] > 0 ? 1u : 0u) << (j * 4)
       | (v[1] > 0 ? 1u : 0u) << (j * 4 + 1)
       | (v[2] > 0 ? 1u : 0u) << (j * 4 + 2)
       | (v[3] > 0 ? 1u : 0u) << (j * 4 + 3);
  }
  adjb[w] = m;
}

// ---------------------------------------------------------------------------
// Finalize: survivors (approx within SURV_THR of approx max) get exact fp32
// rescoring from (fh+fl, gh+gl); tail stays approx in the denominator only.
// Output = sum over survivors of softmax weight * v row.
// ---------------------------------------------------------------------------
__global__ __launch_bounds__(256) void finalize_kernel(
    const uint32_t* __restrict__ cand, const int* __restrict__ cnts,
    const u16* __restrict__ fh, const u16* __restrict__ fl,
    const u16* __restrict__ gh, const u16* __restrict__ gl,
    const u16* __restrict__ vh, float* __restrict__ out)
{
  const int row = blockIdx.x, tid = threadIdx.x, wv = tid >> 6, lane = tid & 63;
  __shared__ float sS[CAP];
  __shared__ int sK[CAP];
  __shared__ float sF[KDIM];
  __shared__ float sEx[MAXS];
  __shared__ int sKs[MAXS];
  __shared__ float red[4];
  __shared__ int nsig;
  int cnt = cnts[row]; cnt = cnt < CAP ? cnt : CAP;
  const int col = tid * 4;
  if (cnt <= 0) {
    f32x4 z = {0.f, 0.f, 0.f, 0.f};
    *(f32x4*)(out + (size_t)row * KDIM + col) = z;
    return;
  }
  if (tid == 0) nsig = 0;
  {  // reconstruct f row in fp32
    us4 h = *(const us4*)(fh + (size_t)row * KDIM + col);
    us4 l = *(const us4*)(fl + (size_t)row * KDIM + col);
    #pragma unroll
    for (int j = 0; j < 4; ++j) sF[col + j] = bf2f(h[j]) + bf2f(l[j]);
  }
  for (int i = tid; i < cnt; i += 256) {
    uint32_t pk = cand[(size_t)row * CAP + i];
    sS[i] = bf2f((u16)(pk >> 16));
    sK[i] = (int)(pk & 0xFFFFu);
  }
  __syncthreads();
  float lm = NEGBIG;
  for (int i = tid; i < cnt; i += 256) lm = fmaxf(lm, sS[i]);
  #pragma unroll
  for (int d = 1; d < 64; d <<= 1) lm = fmaxf(lm, __shfl_xor(lm, d));
  if ((tid & 63) == 0) red[tid >> 6] = lm;
  __syncthreads();
  const float am = fmaxf(fmaxf(red[0], red[1]), fmaxf(red[2], red[3]));
  __syncthreads();
  for (int i = tid; i < cnt; i += 256) {
    if (sS[i] > am - SURV_THR) {
      int p = atomicAdd(&nsig, 1);
      if (p < MAXS) { sKs[p] = sK[i]; sS[i] = NEGBIG; }  // exact path; drop from tail
    }
  }
  __syncthreads();
  const int ns = nsig < MAXS ? nsig : MAXS;
  // exact rescoring: one wave per survivor
  for (int si = wv; si < ns; si += 4) {
    const int key = sKs[si];
    const u16* grh = gh + (size_t)key * KDIM + lane * 16;
    const u16* grl = gl + (size_t)key * KDIM + lane * 16;
    float d = 0.f;
    #pragma unroll
    for (int u = 0; u < 4; ++u) {
      us4 h = *(const us4*)(grh + u * 4);
      us4 l = *(const us4*)(grl + u * 4);
      #pragma unroll
      for (int j = 0; j < 4; ++j)
        d += (bf2f(h[j]) + bf2f(l[j])) * sF[lane * 16 + u * 4 + j];
    }
    #pragma unroll
    for (int dd = 1; dd < 64; dd <<= 1) d += __shfl_xor(d, dd);
    if (lane == 0) sEx[si] = fmaxf(d, 0.f);
  }
  __syncthreads();
  float em = NEGBIG;
  for (int i = tid; i < ns; i += 256) em = fmaxf(em, sEx[i]);
  #pragma unroll
  for (int d = 1; d < 64; d <<= 1) em = fmaxf(em, __shfl_xor(em, d));
  if ((tid & 63) == 0) red[tid >> 6] = em;
  __syncthreads();
  const float m = fmaxf(fmaxf(red[0], red[1]), fmaxf(red[2], red[3]));
  __syncthreads();
  float ls = 0.f;
  for (int i = tid; i < cnt; i += 256) {
    float s = sS[i];
    if (s > NEGBIG * 0.5f) ls += __expf(s - m);     // approx tail
  }
  for (int i = tid; i < ns; i += 256) ls += __expf(sEx[i] - m);
  #pragma unroll
  for (int d = 1; d < 64; d <<= 1) ls += __shfl_xor(ls, d);
  if ((tid & 63) == 0) red[tid >> 6] = ls;
  __syncthreads();
  const float inv = 1.f / (red[0] + red[1] + red[2] + red[3]);
  float a0 = 0.f, a1 = 0.f, a2 = 0.f, a3 = 0.f;
  const u16* vbase = vh + col;
  for (int i = 0; i < ns; ++i) {
    const float wt = __expf(sEx[i] - m) * inv;
    us4 vv = *(const us4*)(vbase + (size_t)sKs[i] * KDIM);
    a0 += wt * bf2f(vv[0]); a1 += wt * bf2f(vv[1]);
    a2 += wt * bf2f(vv[2]); a3 += wt * bf2f(vv[3]);
  }
  f32x4 o = {a0, a1, a2, a3};
  *(f32x4*)(out + (size_t)row * KDIM + col) = o;
}

// ---------------------------------------------------------------------------
// Transpose + hi/lo split of a [K][N] fp32 weight into [N][K] bf16 pair.
// ---------------------------------------------------------------------------
__global__ __launch_bounds__(256) void wsplit_kernel(
    const float* __restrict__ W, u16* __restrict__ th, u16* __restrict__ tl)
{
  __shared__ float tile[32][33];
  const int bx = blockIdx.x, by = blockIdx.y;
  const int tx = threadIdx.x & 31, ty = threadIdx.x >> 5;
  #pragma unroll
  for (int i = 0; i < 4; ++i) {
    int ky = ty + i * 8;
    tile[ky][tx] = W[(size_t)(by * 32 + ky) * KDIM + bx * 32 + tx];
  }
  __syncthreads();
  #pragma unroll
  for (int i = 0; i < 4; ++i) {
    int ny = ty + i * 8;
    float v = tile[tx][ny];
    u16 h = f2bf(v);
    th[(size_t)(bx * 32 + ny) * KDIM + by * 32 + tx] = h;
    tl[(size_t)(bx * 32 + ny) * KDIM + by * 32 + tx] = f2bf(v - bf2f(h));
  }
}

__global__ __launch_bounds__(256) void xsplit_kernel(
    const float* __restrict__ x, u16* __restrict__ xh, u16* __restrict__ xl)
{
  size_t i = ((size_t)blockIdx.x * 256 + threadIdx.x) * 4;
  f32x4 v = *(const f32x4*)(x + i);
  us4 h, l;
  #pragma unroll
  for (int j = 0; j < 4; ++j) {
    h[j] = f2bf(v[j]);
    l[j] = f2bf(v[j] - bf2f(h[j]));
  }
  *(us4*)(xh + i) = h;
  *(us4*)(xl + i) = l;
}

__global__ void ws_report(float* out, size_t n, float v) {
  for (size_t i = (size_t)blockIdx.x * blockDim.x + threadIdx.x; i < n;
       i += (size_t)gridDim.x * blockDim.x) out[i] = v;
}

extern "C" void kernel_launch(void* const* d_in, const int* in_sizes, int n_in,
                              void* d_out, int out_size, void* d_ws, size_t ws_size,
                              hipStream_t stream) {
  (void)in_sizes; (void)n_in;
  const float* x   = (const float*)d_in[0];
  const int*   adj = (const int*)d_in[1];
  const float* Wf  = (const float*)d_in[2];
  const float* bf_ = (const float*)d_in[3];
  const float* Wg  = (const float*)d_in[4];
  const float* bg_ = (const float*)d_in[5];
  const float* W   = (const float*)d_in[6];
  const float* bW_ = (const float*)d_in[7];

  char* p = (char*)d_ws;
  const size_t ND2 = (size_t)NROWS * KDIM * 2;
  const size_t W2  = (size_t)KDIM * KDIM * 2;
  u16* xh = (u16*)p;  p += ND2;
  u16* xl = (u16*)p;  p += ND2;
  u16* fh = (u16*)p;  p += ND2;
  u16* fl = (u16*)p;  p += ND2;
  u16* gh = (u16*)p;  p += ND2;
  u16* gl = (u16*)p;  p += ND2;
  u16* vh = (u16*)p;  p += ND2;
  u16* wfh = (u16*)p; p += W2;
  u16* wfl = (u16*)p; p += W2;
  u16* wgh = (u16*)p; p += W2;
  u16* wgl = (u16*)p; p += W2;
  u16* wh  = (u16*)p; p += W2;
  u16* wl  = (u16*)p; p += W2;
  uint32_t* cand = (uint32_t*)p; p += (size_t)NROWS * CAP * 4;
  int* cnts   = (int*)p; p += (size_t)NROWS * 4;
  int* rowmax = (int*)p; p += (size_t)NROWS * 4;
  const size_t need = (size_t)(p - (char*)d_ws);
  if (ws_size < need) {
    ws_report<<<256, 256, 0, stream>>>((float*)d_out, (size_t)out_size, (float)ws_size);
    return;
  }
  uint32_t* adjb = (uint32_t*)xl;   // aliases xl after pre-GEMMs are done

  auto kf = gemm_kernel<3, true>;
  auto kv = gemm_kernel<1, false>;
  hipFuncSetAttribute((const void*)kf, hipFuncAttributeMaxDynamicSharedMemorySize, 131072);
  hipFuncSetAttribute((const void*)kv, hipFuncAttributeMaxDynamicSharedMemorySize, 65536);
  hipFuncSetAttribute((const void*)scores_kernel, hipFuncAttributeMaxDynamicSharedMemorySize, 65536);

  hipMemsetAsync(cnts, 0, (size_t)NROWS * 8, stream);   // cnts + rowmax (0 == 0.0f)
  wsplit_kernel<<<dim3(32, 32), 256, 0, stream>>>(Wf, wfh, wfl);
  wsplit_kernel<<<dim3(32, 32), 256, 0, stream>>>(Wg, wgh, wgl);
  wsplit_kernel<<<dim3(32, 32), 256, 0, stream>>>(W, wh, wl);
  xsplit_kernel<<<(NROWS * KDIM) / (256 * 4), 256, 0, stream>>>(x, xh, xl);

  // f = x@Wf + bf, g = x@Wg + bg (split-3, hi+lo out), v = x@W + bW (1 pass)
  kf<<<dim3(64, 8), 512, 131072, stream>>>(xh, xl, wfh, wfl, bf_, fh, fl);
  kf<<<dim3(64, 8), 512, 131072, stream>>>(xh, xl, wgh, wgl, bg_, gh, gl);
  kv<<<dim3(64, 8), 512, 65536, stream>>>(xh, xl, wh, wl, bW_, vh, nullptr);
  adjpack_kernel<<<(NROWS * (NROWS / 32)) / 256, 256, 0, stream>>>(adj, adjb);
  // single-pass bf16 scores sweep + bounded candidate emission
  scores_kernel<<<dim3(512), 512, 65536, stream>>>(fh, gh, adjb, cand, cnts, rowmax);
  // exact rescoring of survivors + softmax + v gather
  finalize_kernel<<<NROWS, 256, 0, stream>>>(cand, cnts, fh, fl, gh, gl, vh,
                                             (float*)d_out);
}

// Round 6
// 565.572 us; speedup vs baseline: 3.9803x; 1.1101x over previous
//
#include <hip/hip_runtime.h>
#include <stdint.h>

#define NROWS 8192
#define KDIM  1024
#define CAP   512
#define NEGBIG (-9.0e15f)
#define EMIT_THR 16.0f
#define SURV_THR 13.5f
#define MAXS  128

typedef __attribute__((ext_vector_type(8))) __bf16 bf16x8;
typedef __attribute__((ext_vector_type(4))) float f32x4;
typedef __attribute__((ext_vector_type(4))) unsigned short us4;
typedef __attribute__((ext_vector_type(4))) int i32x4;
typedef unsigned short u16;

__device__ __forceinline__ u16 f2bf(float f) {
  unsigned u = __float_as_uint(f);
  u += 0x7fffu + ((u >> 16) & 1u);
  return (u16)(u >> 16);
}
__device__ __forceinline__ float bf2f(u16 h) {
  return __uint_as_float(((unsigned)h) << 16);
}

__device__ __forceinline__ void glds16(const void* g, const char* lds) {
  __builtin_amdgcn_global_load_lds(
      (const __attribute__((address_space(1))) unsigned int*)(uintptr_t)g,
      (__attribute__((address_space(3))) unsigned int*)(uintptr_t)lds, 16, 0, 0);
}

__device__ __forceinline__ f32x4 mfma16(bf16x8 a, bf16x8 b, f32x4 c) {
  return __builtin_amdgcn_mfma_f32_16x16x32_bf16(a, b, c, 0, 0, 0);
}

// ---------------------------------------------------------------------------
// Pre-GEMM (R4-proven): C[128x128] = A@B^T, split-3 (NSPLIT=3) or 1-pass.
// ---------------------------------------------------------------------------
template<int NSPLIT, bool SPLITOUT>
__global__ __launch_bounds__(512, 1) void gemm_kernel(
    const u16* __restrict__ ah, const u16* __restrict__ al,
    const u16* __restrict__ bh, const u16* __restrict__ bl,
    const float* __restrict__ bias, u16* __restrict__ ch, u16* __restrict__ cl)
{
  extern __shared__ char smem[];
  constexpr int BUFS = (NSPLIT == 3) ? 65536 : 32768;
  constexpr int AHO = 0, ALO = 16384;
  constexpr int BHO = (NSPLIT == 3) ? 32768 : 16384;
  constexpr int BLO = 49152;
  constexpr int NT = KDIM / 64;

  const int tid = threadIdx.x, w = tid >> 6, lane = tid & 63;
  const int wr = w >> 2, wc = w & 3;
  const int bx = blockIdx.x, by = blockIdx.y;
  const int arow0 = bx * 128, bcol0 = by * 128;

  const int srow = w * 16 + (lane >> 3);
  const int scol = ((lane & 7) ^ (lane >> 3)) * 8;
  const size_t sgA = (size_t)(arow0 + srow) * KDIM + scol;
  const size_t sgB = (size_t)(bcol0 + srow) * KDIM + scol;
  const int ldsw = w * 2048;

  auto stg = [&](const u16* src, size_t sg, int kt, int ldsoff) {
    const u16* sp = src + sg + kt * 64;
    glds16(sp,            smem + ldsoff + ldsw);
    glds16(sp + 8 * KDIM, smem + ldsoff + ldsw + 1024);
  };

  const int fa = (wr * 64 + (lane & 15)) * 128;
  const int fb = (wc * 32 + (lane & 15)) * 128;
  const int kqx0 = (((lane >> 4)    ) ^ (lane & 7)) * 16;
  const int kqx1 = (((lane >> 4) + 4) ^ (lane & 7)) * 16;

  stg(ah, sgA, 0, AHO); stg(bh, sgB, 0, BHO);
  if constexpr (NSPLIT == 3) { stg(al, sgA, 0, ALO); stg(bl, sgB, 0, BLO); }
  else { stg(ah, sgA, 1, AHO + BUFS); stg(bh, sgB, 1, BHO + BUFS); }

  f32x4 acc[4][2];
  #pragma unroll
  for (int m = 0; m < 4; ++m) {
    acc[m][0] = f32x4{0.f, 0.f, 0.f, 0.f};
    acc[m][1] = f32x4{0.f, 0.f, 0.f, 0.f};
  }

  for (int t = 0; t < NT; ++t) {
    const int bo  = (t & 1) * BUFS;
    const int bo2 = ((t + 1) & 1) * BUFS;

    if (NSPLIT == 1 && t == NT - 1) asm volatile("s_waitcnt vmcnt(0)" ::: "memory");
    else                            asm volatile("s_waitcnt vmcnt(4)" ::: "memory");
    __builtin_amdgcn_s_barrier();
    __builtin_amdgcn_sched_barrier(0);

    if (NSPLIT == 3 && t + 1 < NT) {
      stg(ah, sgA, t + 1, AHO + bo2);
      stg(bh, sgB, t + 1, BHO + bo2);
    }

    bf16x8 a0[4][2], b0[2][2];
    #pragma unroll
    for (int m = 0; m < 4; ++m) {
      a0[m][0] = *(const bf16x8*)(smem + AHO + bo + fa + m * 2048 + kqx0);
      a0[m][1] = *(const bf16x8*)(smem + AHO + bo + fa + m * 2048 + kqx1);
    }
    #pragma unroll
    for (int n = 0; n < 2; ++n) {
      b0[n][0] = *(const bf16x8*)(smem + BHO + bo + fb + n * 2048 + kqx0);
      b0[n][1] = *(const bf16x8*)(smem + BHO + bo + fb + n * 2048 + kqx1);
    }
    __builtin_amdgcn_s_setprio(1);
    #pragma unroll
    for (int kq = 0; kq < 2; ++kq)
      #pragma unroll
      for (int m = 0; m < 4; ++m)
        #pragma unroll
        for (int n = 0; n < 2; ++n)
          acc[m][n] = mfma16(a0[m][kq], b0[n][kq], acc[m][n]);
    __builtin_amdgcn_s_setprio(0);
    asm volatile("s_waitcnt lgkmcnt(0)" ::: "memory");

    if constexpr (NSPLIT == 3) {
      if (t + 1 < NT) asm volatile("s_waitcnt vmcnt(4)" ::: "memory");
      else            asm volatile("s_waitcnt vmcnt(0)" ::: "memory");
      __builtin_amdgcn_s_barrier();
      __builtin_amdgcn_sched_barrier(0);

      if (t + 1 < NT) {
        stg(al, sgA, t + 1, ALO + bo2);
        stg(bl, sgB, t + 1, BLO + bo2);
      }
      bf16x8 a1[4][2], b1[2][2];
      #pragma unroll
      for (int m = 0; m < 4; ++m) {
        a1[m][0] = *(const bf16x8*)(smem + ALO + bo + fa + m * 2048 + kqx0);
        a1[m][1] = *(const bf16x8*)(smem + ALO + bo + fa + m * 2048 + kqx1);
      }
      #pragma unroll
      for (int n = 0; n < 2; ++n) {
        b1[n][0] = *(const bf16x8*)(smem + BLO + bo + fb + n * 2048 + kqx0);
        b1[n][1] = *(const bf16x8*)(smem + BLO + bo + fb + n * 2048 + kqx1);
      }
      __builtin_amdgcn_s_setprio(1);
      #pragma unroll
      for (int kq = 0; kq < 2; ++kq)
        #pragma unroll
        for (int m = 0; m < 4; ++m)
          #pragma unroll
          for (int n = 0; n < 2; ++n)
            acc[m][n] = mfma16(a1[m][kq], b0[n][kq], acc[m][n]);
      #pragma unroll
      for (int kq = 0; kq < 2; ++kq)
        #pragma unroll
        for (int m = 0; m < 4; ++m)
          #pragma unroll
          for (int n = 0; n < 2; ++n)
            acc[m][n] = mfma16(a0[m][kq], b1[n][kq], acc[m][n]);
      __builtin_amdgcn_s_setprio(0);
      asm volatile("s_waitcnt lgkmcnt(0)" ::: "memory");
    } else {
      __builtin_amdgcn_s_barrier();
      if (t + 2 < NT) {
        stg(ah, sgA, t + 2, AHO + bo);
        stg(bh, sgB, t + 2, BHO + bo);
      }
    }
  }

  const int l15 = lane & 15, g4 = (lane >> 4) << 2;
  const int colb = bcol0 + wc * 32 + l15;
  const float bi0 = bias[colb], bi1 = bias[colb + 16];
  #pragma unroll
  for (int m = 0; m < 4; ++m) {
    #pragma unroll
    for (int j = 0; j < 4; ++j) {
      const int row = arow0 + wr * 64 + m * 16 + g4 + j;
      float v0 = acc[m][0][j] + bi0, v1 = acc[m][1][j] + bi1;
      u16 h0 = f2bf(v0), h1 = f2bf(v1);
      ch[(size_t)row * KDIM + colb] = h0;
      ch[(size_t)row * KDIM + colb + 16] = h1;
      if constexpr (SPLITOUT) {
        cl[(size_t)row * KDIM + colb] = f2bf(v0 - bf2f(h0));
        cl[(size_t)row * KDIM + colb + 16] = f2bf(v1 - bf2f(h1));
      }
    }
  }
}

// ---------------------------------------------------------------------------
// Scores sweep, 256x256 tile: relu(fh@gh^T), adjacency mask, running-max
// candidate emission. 8 waves (2Mx4N), wave tile 128x64 (acc[8][4]), BK=64,
// 2x64KB LDS dbuf. Per K-tile: 4 sched_barrier phases (reads amortized
// 24 ds_read : 64 MFMA), ONE s_barrier + lgkm(0)+vmcnt(0) at the boundary
// (loads issued a full tile earlier -> drain is cheap). 256 persistent wgs:
// 32 row-slabs x 8 siblings, 4 key-tiles each, global rowmax sharing.
// ---------------------------------------------------------------------------
__global__ __launch_bounds__(512, 2) void scores_kernel(
    const u16* __restrict__ fh, const u16* __restrict__ gh,
    const uint32_t* __restrict__ adjb, uint32_t* __restrict__ cand,
    int* __restrict__ cnts, int* rowmax)
{
  extern __shared__ char smem[];
  constexpr int BUFS = 65536, BOFF = 32768;
  constexpr int NKT = 64;                 // 4 key-tiles x 16 K-tiles

  const int tid = threadIdx.x, w = tid >> 6, lane = tid & 63;
  const int wr = w >> 2, wc = w & 3;
  const int l15 = lane & 15, g4 = (lane >> 4) << 2;

  // 256 wgs: XCD x hosts row-slabs x*4..x*4+3; 8 siblings per slab.
  const int xcd = blockIdx.x & 7, idx = blockIdx.x >> 3;
  const int bx  = xcd * 4 + (idx & 3);
  const int sub = idx >> 2;               // sibling 0..7
  const int arow0 = bx * 256;

  // staging: wave w covers rows [w*32, w*32+32) of both 256-row panels
  const int srow = w * 32 + (lane >> 3);
  const int scol = ((lane & 7) ^ ((lane >> 3) & 7)) * 8;
  const int ldsw = w * 4096;

  auto stageA = [&](int kt, int bo) {
    const int t = kt & 15;
    const u16* pa = fh + (size_t)(arow0 + srow) * KDIM + scol + t * 64;
    #pragma unroll
    for (int r = 0; r < 4; ++r)
      glds16(pa + r * 8 * KDIM, smem + bo + ldsw + r * 1024);
  };
  auto stageB = [&](int kt, int bo) {
    const int it = kt >> 4, t = kt & 15;
    const int by = sub + 8 * it;
    const u16* pb = gh + (size_t)(by * 256 + srow) * KDIM + scol + t * 64;
    #pragma unroll
    for (int r = 0; r < 4; ++r)
      glds16(pb + r * 8 * KDIM, smem + bo + BOFF + ldsw + r * 1024);
  };

  const int fa = (wr * 128 + l15) * 128;          // + m*2048
  const int fb = BOFF + (wc * 64 + l15) * 128;    // + n*2048
  const int kx0 = (((lane >> 4)    ) ^ (lane & 7)) * 16;
  const int kx1 = (((lane >> 4) + 4) ^ (lane & 7)) * 16;

  f32x4 acc[8][4];
  #pragma unroll
  for (int m = 0; m < 8; ++m)
    #pragma unroll
    for (int n = 0; n < 4; ++n) acc[m][n] = f32x4{0.f, 0.f, 0.f, 0.f};

  const unsigned long long lmask = (1ull << lane) - 1ull;
  const unsigned long long gm = 0xFFFFull << (lane & 48);

  stageA(0, 0); stageB(0, 0);
  asm volatile("s_waitcnt vmcnt(0)" ::: "memory");
  __builtin_amdgcn_s_barrier();

  for (int kt = 0; kt < NKT; ++kt) {
    const int bo  = (kt & 1) * BUFS;
    const int bo2 = ((kt + 1) & 1) * BUFS;

    bf16x8 a[4][2], b[4][2];
    // ---- phase 0: issue ALL of tile kt+1's staging, read a0-3 + b0-1,
    //      MFMA m0-3 x n0-1
    if (kt + 1 < NKT) { stageA(kt + 1, bo2); stageB(kt + 1, bo2); }
    #pragma unroll
    for (int m = 0; m < 4; ++m) {
      a[m][0] = *(const bf16x8*)(smem + bo + fa + m * 2048 + kx0);
      a[m][1] = *(const bf16x8*)(smem + bo + fa + m * 2048 + kx1);
    }
    #pragma unroll
    for (int n = 0; n < 2; ++n) {
      b[n][0] = *(const bf16x8*)(smem + bo + fb + n * 2048 + kx0);
      b[n][1] = *(const bf16x8*)(smem + bo + fb + n * 2048 + kx1);
    }
    __builtin_amdgcn_sched_barrier(0);
    __builtin_amdgcn_s_setprio(1);
    #pragma unroll
    for (int kq = 0; kq < 2; ++kq)
      #pragma unroll
      for (int m = 0; m < 4; ++m)
        #pragma unroll
        for (int n = 0; n < 2; ++n)
          acc[m][n] = mfma16(a[m][kq], b[n][kq], acc[m][n]);
    __builtin_amdgcn_s_setprio(0);
    __builtin_amdgcn_sched_barrier(0);

    // ---- phase 1: read b2-3, MFMA m0-3 x n2-3
    #pragma unroll
    for (int n = 2; n < 4; ++n) {
      b[n][0] = *(const bf16x8*)(smem + bo + fb + n * 2048 + kx0);
      b[n][1] = *(const bf16x8*)(smem + bo + fb + n * 2048 + kx1);
    }
    __builtin_amdgcn_sched_barrier(0);
    __builtin_amdgcn_s_setprio(1);
    #pragma unroll
    for (int kq = 0; kq < 2; ++kq)
      #pragma unroll
      for (int m = 0; m < 4; ++m)
        #pragma unroll
        for (int n = 2; n < 4; ++n)
          acc[m][n] = mfma16(a[m][kq], b[n][kq], acc[m][n]);
    __builtin_amdgcn_s_setprio(0);
    __builtin_amdgcn_sched_barrier(0);

    // ---- phase 2: reload a with m4-7 (same regs), MFMA m4-7 x n2-3
    #pragma unroll
    for (int m = 0; m < 4; ++m) {
      a[m][0] = *(const bf16x8*)(smem + bo + fa + (m + 4) * 2048 + kx0);
      a[m][1] = *(const bf16x8*)(smem + bo + fa + (m + 4) * 2048 + kx1);
    }
    __builtin_amdgcn_sched_barrier(0);
    __builtin_amdgcn_s_setprio(1);
    #pragma unroll
    for (int kq = 0; kq < 2; ++kq)
      #pragma unroll
      for (int m = 0; m < 4; ++m)
        #pragma unroll
        for (int n = 2; n < 4; ++n)
          acc[m + 4][n] = mfma16(a[m][kq], b[n][kq], acc[m + 4][n]);
    __builtin_amdgcn_s_setprio(0);
    __builtin_amdgcn_sched_barrier(0);

    // ---- phase 3: MFMA m4-7 x n0-1
    __builtin_amdgcn_s_setprio(1);
    #pragma unroll
    for (int kq = 0; kq < 2; ++kq)
      #pragma unroll
      for (int m = 0; m < 4; ++m)
        #pragma unroll
        for (int n = 0; n < 2; ++n)
          acc[m + 4][n] = mfma16(a[m][kq], b[n][kq], acc[m + 4][n]);
    __builtin_amdgcn_s_setprio(0);

    // ---- boundary: drain own ds_reads (WAR) + own glds (RAW), publish
    asm volatile("s_waitcnt lgkmcnt(0)" ::: "memory");
    asm volatile("s_waitcnt vmcnt(0)" ::: "memory");
    __builtin_amdgcn_s_barrier();

    if ((kt & 15) == 15) {
      // ---- key-tile epilogue: mask, running-max, bounded emission
      const int it = kt >> 4;
      const int bcol0 = (sub + 8 * it) * 256;
      const int keyb = bcol0 + wc * 64 + l15;
      #pragma unroll
      for (int m = 0; m < 8; ++m) {
        #pragma unroll
        for (int j = 0; j < 4; ++j) {
          const int row = arow0 + wr * 128 + m * 16 + g4 + j;
          const uint32_t* ap = adjb + (size_t)row * (NROWS / 32) + (bcol0 >> 5) + wc * 2;
          const uint32_t w0 = ap[0], w1 = ap[1];
          float sv[4]; float rm = NEGBIG;
          #pragma unroll
          for (int n = 0; n < 4; ++n) {
            float v = fmaxf(acc[m][n][j], 0.f);
            uint32_t bit = ((n < 2 ? w0 : w1) >> ((n & 1) * 16 + l15)) & 1u;
            sv[n] = bit ? v : NEGBIG;
            rm = fmaxf(rm, sv[n]);
          }
          rm = fmaxf(rm, __shfl_xor(rm, 1));
          rm = fmaxf(rm, __shfl_xor(rm, 2));
          rm = fmaxf(rm, __shfl_xor(rm, 4));
          rm = fmaxf(rm, __shfl_xor(rm, 8));
          const float old = __int_as_float(rowmax[row]);   // stale-tolerant
          const float mr = fmaxf(rm, old);
          if (l15 == 0 && rm > old) atomicMax(rowmax + row, __float_as_int(rm));
          const float thr = mr - EMIT_THR;
          unsigned long long mm[4]; int c4[4];
          int tot = 0;
          #pragma unroll
          for (int n = 0; n < 4; ++n) {
            mm[n] = __ballot(sv[n] > thr);
            c4[n] = __popcll(mm[n] & gm);
            tot += c4[n];
          }
          int base = 0;
          if (l15 == 0 && tot > 0) base = atomicAdd(cnts + row, tot);
          base = __shfl(base, lane & 48);
          int pref = 0;
          #pragma unroll
          for (int n = 0; n < 4; ++n) {
            const int p = base + pref + __popcll(mm[n] & gm & lmask);
            if ((sv[n] > thr) && p < CAP)
              cand[(size_t)row * CAP + p] =
                  ((uint32_t)f2bf(sv[n]) << 16) | (uint32_t)(keyb + n * 16);
            pref += c4[n];
          }
        }
      }
      #pragma unroll
      for (int m = 0; m < 8; ++m)
        #pragma unroll
        for (int n = 0; n < 4; ++n) acc[m][n] = f32x4{0.f, 0.f, 0.f, 0.f};
    }
  }
}

// ---------------------------------------------------------------------------
// adj (int32 0/1, 268 MB) -> bitmask (8 MB). BW-bound single pass.
// ---------------------------------------------------------------------------
__global__ __launch_bounds__(256) void adjpack_kernel(
    const int* __restrict__ adj, uint32_t* __restrict__ adjb)
{
  size_t w = (size_t)blockIdx.x * 256 + threadIdx.x;
  const int* src = adj + (w << 5);
  uint32_t m = 0;
  #pragma unroll
  for (int j = 0; j < 8; ++j) {
    i32x4 v = *(const i32x4*)(src + j * 4);
    m |= (v[0] > 0 ? 1u : 0u) << (j * 4)
       | (v[1] > 0 ? 1u : 0u) << (j * 4 + 1)
       | (v[2] > 0 ? 1u : 0u) << (j * 4 + 2)
       | (v[3] > 0 ? 1u : 0u) << (j * 4 + 3);
  }
  adjb[w] = m;
}

// ---------------------------------------------------------------------------
// Finalize: survivors (within SURV_THR of approx max) rescored exactly in
// fp32 from (fh+fl, gh+gl); tail stays approx in the denominator only.
// ---------------------------------------------------------------------------
__global__ __launch_bounds__(256) void finalize_kernel(
    const uint32_t* __restrict__ cand, const int* __restrict__ cnts,
    const u16* __restrict__ fh, const u16* __restrict__ fl,
    const u16* __restrict__ gh, const u16* __restrict__ gl,
    const u16* __restrict__ vh, float* __restrict__ out)
{
  const int row = blockIdx.x, tid = threadIdx.x, wv = tid >> 6, lane = tid & 63;
  __shared__ float sS[CAP];
  __shared__ int sK[CAP];
  __shared__ float sF[KDIM];
  __shared__ float sEx[MAXS];
  __shared__ int sKs[MAXS];
  __shared__ float red[4];
  __shared__ int nsig;
  int cnt = cnts[row]; cnt = cnt < CAP ? cnt : CAP;
  const int col = tid * 4;
  if (cnt <= 0) {
    f32x4 z = {0.f, 0.f, 0.f, 0.f};
    *(f32x4*)(out + (size_t)row * KDIM + col) = z;
    return;
  }
  if (tid == 0) nsig = 0;
  {
    us4 h = *(const us4*)(fh + (size_t)row * KDIM + col);
    us4 l = *(const us4*)(fl + (size_t)row * KDIM + col);
    #pragma unroll
    for (int j = 0; j < 4; ++j) sF[col + j] = bf2f(h[j]) + bf2f(l[j]);
  }
  for (int i = tid; i < cnt; i += 256) {
    uint32_t pk = cand[(size_t)row * CAP + i];
    sS[i] = bf2f((u16)(pk >> 16));
    sK[i] = (int)(pk & 0xFFFFu);
  }
  __syncthreads();
  float lm = NEGBIG;
  for (int i = tid; i < cnt; i += 256) lm = fmaxf(lm, sS[i]);
  #pragma unroll
  for (int d = 1; d < 64; d <<= 1) lm = fmaxf(lm, __shfl_xor(lm, d));
  if ((tid & 63) == 0) red[tid >> 6] = lm;
  __syncthreads();
  const float am = fmaxf(fmaxf(red[0], red[1]), fmaxf(red[2], red[3]));
  __syncthreads();
  for (int i = tid; i < cnt; i += 256) {
    if (sS[i] > am - SURV_THR) {
      int p = atomicAdd(&nsig, 1);
      if (p < MAXS) { sKs[p] = sK[i]; sS[i] = NEGBIG; }
    }
  }
  __syncthreads();
  const int ns = nsig < MAXS ? nsig : MAXS;
  for (int si = wv; si < ns; si += 4) {
    const int key = sKs[si];
    const u16* grh = gh + (size_t)key * KDIM + lane * 16;
    const u16* grl = gl + (size_t)key * KDIM + lane * 16;
    float d = 0.f;
    #pragma unroll
    for (int u = 0; u < 4; ++u) {
      us4 h = *(const us4*)(grh + u * 4);
      us4 l = *(const us4*)(grl + u * 4);
      #pragma unroll
      for (int j = 0; j < 4; ++j)
        d += (bf2f(h[j]) + bf2f(l[j])) * sF[lane * 16 + u * 4 + j];
    }
    #pragma unroll
    for (int dd = 1; dd < 64; dd <<= 1) d += __shfl_xor(d, dd);
    if (lane == 0) sEx[si] = fmaxf(d, 0.f);
  }
  __syncthreads();
  float em = NEGBIG;
  for (int i = tid; i < ns; i += 256) em = fmaxf(em, sEx[i]);
  #pragma unroll
  for (int d = 1; d < 64; d <<= 1) em = fmaxf(em, __shfl_xor(em, d));
  if ((tid & 63) == 0) red[tid >> 6] = em;
  __syncthreads();
  const float m = fmaxf(fmaxf(red[0], red[1]), fmaxf(red[2], red[3]));
  __syncthreads();
  float ls = 0.f;
  for (int i = tid; i < cnt; i += 256) {
    float s = sS[i];
    if (s > NEGBIG * 0.5f) ls += __expf(s - m);
  }
  for (int i = tid; i < ns; i += 256) ls += __expf(sEx[i] - m);
  #pragma unroll
  for (int d = 1; d < 64; d <<= 1) ls += __shfl_xor(ls, d);
  if ((tid & 63) == 0) red[tid >> 6] = ls;
  __syncthreads();
  const float inv = 1.f / (red[0] + red[1] + red[2] + red[3]);
  float a0 = 0.f, a1 = 0.f, a2 = 0.f, a3 = 0.f;
  const u16* vbase = vh + col;
  for (int i = 0; i < ns; ++i) {
    const float wt = __expf(sEx[i] - m) * inv;
    us4 vv = *(const us4*)(vbase + (size_t)sKs[i] * KDIM);
    a0 += wt * bf2f(vv[0]); a1 += wt * bf2f(vv[1]);
    a2 += wt * bf2f(vv[2]); a3 += wt * bf2f(vv[3]);
  }
  f32x4 o = {a0, a1, a2, a3};
  *(f32x4*)(out + (size_t)row * KDIM + col) = o;
}

// ---------------------------------------------------------------------------
// Transpose + hi/lo split of a [K][N] fp32 weight into [N][K] bf16 pair.
// ---------------------------------------------------------------------------
__global__ __launch_bounds__(256) void wsplit_kernel(
    const float* __restrict__ W, u16* __restrict__ th, u16* __restrict__ tl)
{
  __shared__ float tile[32][33];
  const int bx = blockIdx.x, by = blockIdx.y;
  const int tx = threadIdx.x & 31, ty = threadIdx.x >> 5;
  #pragma unroll
  for (int i = 0; i < 4; ++i) {
    int ky = ty + i * 8;
    tile[ky][tx] = W[(size_t)(by * 32 + ky) * KDIM + bx * 32 + tx];
  }
  __syncthreads();
  #pragma unroll
  for (int i = 0; i < 4; ++i) {
    int ny = ty + i * 8;
    float v = tile[tx][ny];
    u16 h = f2bf(v);
    th[(size_t)(bx * 32 + ny) * KDIM + by * 32 + tx] = h;
    tl[(size_t)(bx * 32 + ny) * KDIM + by * 32 + tx] = f2bf(v - bf2f(h));
  }
}

__global__ __launch_bounds__(256) void xsplit_kernel(
    const float* __restrict__ x, u16* __restrict__ xh, u16* __restrict__ xl)
{
  size_t i = ((size_t)blockIdx.x * 256 + threadIdx.x) * 4;
  f32x4 v = *(const f32x4*)(x + i);
  us4 h, l;
  #pragma unroll
  for (int j = 0; j < 4; ++j) {
    h[j] = f2bf(v[j]);
    l[j] = f2bf(v[j] - bf2f(h[j]));
  }
  *(us4*)(xh + i) = h;
  *(us4*)(xl + i) = l;
}

__global__ void ws_report(float* out, size_t n, float v) {
  for (size_t i = (size_t)blockIdx.x * blockDim.x + threadIdx.x; i < n;
       i += (size_t)gridDim.x * blockDim.x) out[i] = v;
}

extern "C" void kernel_launch(void* const* d_in, const int* in_sizes, int n_in,
                              void* d_out, int out_size, void* d_ws, size_t ws_size,
                              hipStream_t stream) {
  (void)in_sizes; (void)n_in;
  const float* x   = (const float*)d_in[0];
  const int*   adj = (const int*)d_in[1];
  const float* Wf  = (const float*)d_in[2];
  const float* bf_ = (const float*)d_in[3];
  const float* Wg  = (const float*)d_in[4];
  const float* bg_ = (const float*)d_in[5];
  const float* W   = (const float*)d_in[6];
  const float* bW_ = (const float*)d_in[7];

  char* p = (char*)d_ws;
  const size_t ND2 = (size_t)NROWS * KDIM * 2;
  const size_t W2  = (size_t)KDIM * KDIM * 2;
  u16* xh = (u16*)p;  p += ND2;
  u16* xl = (u16*)p;  p += ND2;
  u16* fh = (u16*)p;  p += ND2;
  u16* fl = (u16*)p;  p += ND2;
  u16* gh = (u16*)p;  p += ND2;
  u16* gl = (u16*)p;  p += ND2;
  u16* vh = (u16*)p;  p += ND2;
  u16* wfh = (u16*)p; p += W2;
  u16* wfl = (u16*)p; p += W2;
  u16* wgh = (u16*)p; p += W2;
  u16* wgl = (u16*)p; p += W2;
  u16* wh  = (u16*)p; p += W2;
  u16* wl  = (u16*)p; p += W2;
  uint32_t* cand = (uint32_t*)p; p += (size_t)NROWS * CAP * 4;
  int* cnts   = (int*)p; p += (size_t)NROWS * 4;
  int* rowmax = (int*)p; p += (size_t)NROWS * 4;
  const size_t need = (size_t)(p - (char*)d_ws);
  if (ws_size < need) {
    ws_report<<<256, 256, 0, stream>>>((float*)d_out, (size_t)out_size, (float)ws_size);
    return;
  }
  uint32_t* adjb = (uint32_t*)xl;   // aliases xl after pre-GEMMs are done

  auto kf = gemm_kernel<3, true>;
  auto kv = gemm_kernel<1, false>;
  hipFuncSetAttribute((const void*)kf, hipFuncAttributeMaxDynamicSharedMemorySize, 131072);
  hipFuncSetAttribute((const void*)kv, hipFuncAttributeMaxDynamicSharedMemorySize, 65536);
  hipFuncSetAttribute((const void*)scores_kernel, hipFuncAttributeMaxDynamicSharedMemorySize, 131072);

  hipMemsetAsync(cnts, 0, (size_t)NROWS * 8, stream);   // cnts + rowmax (0 == 0.0f)
  wsplit_kernel<<<dim3(32, 32), 256, 0, stream>>>(Wf, wfh, wfl);
  wsplit_kernel<<<dim3(32, 32), 256, 0, stream>>>(Wg, wgh, wgl);
  wsplit_kernel<<<dim3(32, 32), 256, 0, stream>>>(W, wh, wl);
  xsplit_kernel<<<(NROWS * KDIM) / (256 * 4), 256, 0, stream>>>(x, xh, xl);

  // f = x@Wf + bf, g = x@Wg + bg (split-3, hi+lo out), v = x@W + bW (1 pass)
  kf<<<dim3(64, 8), 512, 131072, stream>>>(xh, xl, wfh, wfl, bf_, fh, fl);
  kf<<<dim3(64, 8), 512, 131072, stream>>>(xh, xl, wgh, wgl, bg_, gh, gl);
  kv<<<dim3(64, 8), 512, 65536, stream>>>(xh, xl, wh, wl, bW_, vh, nullptr);
  adjpack_kernel<<<(NROWS * (NROWS / 32)) / 256, 256, 0, stream>>>(adj, adjb);
  // 256x256-tile single-pass bf16 scores sweep + bounded candidate emission
  scores_kernel<<<dim3(256), 512, 131072, stream>>>(fh, gh, adjb, cand, cnts, rowmax);
  // exact rescoring of survivors + softmax + v gather
  finalize_kernel<<<NROWS, 256, 0, stream>>>(cand, cnts, fh, fl, gh, gl, vh,
                                             (float*)d_out);
}

// Round 7
// 555.006 us; speedup vs baseline: 4.0560x; 1.0190x over previous
//
#include <hip/hip_runtime.h>
#include <stdint.h>

#define NROWS 8192
#define KDIM  1024
#define CAP   512
#define NEGBIG (-9.0e15f)
#define EMIT_THR 16.0f
#define SURV_THR 13.5f
#define MAXS  128

typedef __attribute__((ext_vector_type(8))) __bf16 bf16x8;
typedef __attribute__((ext_vector_type(4))) float f32x4;
typedef __attribute__((ext_vector_type(4))) unsigned short us4;
typedef __attribute__((ext_vector_type(4))) int i32x4;
typedef unsigned short u16;

__device__ __forceinline__ u16 f2bf(float f) {
  unsigned u = __float_as_uint(f);
  u += 0x7fffu + ((u >> 16) & 1u);
  return (u16)(u >> 16);
}
__device__ __forceinline__ float bf2f(u16 h) {
  return __uint_as_float(((unsigned)h) << 16);
}

__device__ __forceinline__ void glds16(const void* g, const char* lds) {
  __builtin_amdgcn_global_load_lds(
      (const __attribute__((address_space(1))) unsigned int*)(uintptr_t)g,
      (__attribute__((address_space(3))) unsigned int*)(uintptr_t)lds, 16, 0, 0);
}

__device__ __forceinline__ f32x4 mfma16(bf16x8 a, bf16x8 b, f32x4 c) {
  return __builtin_amdgcn_mfma_f32_16x16x32_bf16(a, b, c, 0, 0, 0);
}

// ---------------------------------------------------------------------------
// Pre-GEMM (R4-proven): C[128x128] = A@B^T, split-3 (NSPLIT=3) or 1-pass.
// ---------------------------------------------------------------------------
template<int NSPLIT, bool SPLITOUT>
__global__ __launch_bounds__(512, 1) void gemm_kernel(
    const u16* __restrict__ ah, const u16* __restrict__ al,
    const u16* __restrict__ bh, const u16* __restrict__ bl,
    const float* __restrict__ bias, u16* __restrict__ ch, u16* __restrict__ cl)
{
  extern __shared__ char smem[];
  constexpr int BUFS = (NSPLIT == 3) ? 65536 : 32768;
  constexpr int AHO = 0, ALO = 16384;
  constexpr int BHO = (NSPLIT == 3) ? 32768 : 16384;
  constexpr int BLO = 49152;
  constexpr int NT = KDIM / 64;

  const int tid = threadIdx.x, w = tid >> 6, lane = tid & 63;
  const int wr = w >> 2, wc = w & 3;
  const int bx = blockIdx.x, by = blockIdx.y;
  const int arow0 = bx * 128, bcol0 = by * 128;

  const int srow = w * 16 + (lane >> 3);
  const int scol = ((lane & 7) ^ (lane >> 3)) * 8;
  const size_t sgA = (size_t)(arow0 + srow) * KDIM + scol;
  const size_t sgB = (size_t)(bcol0 + srow) * KDIM + scol;
  const int ldsw = w * 2048;

  auto stg = [&](const u16* src, size_t sg, int kt, int ldsoff) {
    const u16* sp = src + sg + kt * 64;
    glds16(sp,            smem + ldsoff + ldsw);
    glds16(sp + 8 * KDIM, smem + ldsoff + ldsw + 1024);
  };

  const int fa = (wr * 64 + (lane & 15)) * 128;
  const int fb = (wc * 32 + (lane & 15)) * 128;
  const int kqx0 = (((lane >> 4)    ) ^ (lane & 7)) * 16;
  const int kqx1 = (((lane >> 4) + 4) ^ (lane & 7)) * 16;

  stg(ah, sgA, 0, AHO); stg(bh, sgB, 0, BHO);
  if constexpr (NSPLIT == 3) { stg(al, sgA, 0, ALO); stg(bl, sgB, 0, BLO); }
  else { stg(ah, sgA, 1, AHO + BUFS); stg(bh, sgB, 1, BHO + BUFS); }

  f32x4 acc[4][2];
  #pragma unroll
  for (int m = 0; m < 4; ++m) {
    acc[m][0] = f32x4{0.f, 0.f, 0.f, 0.f};
    acc[m][1] = f32x4{0.f, 0.f, 0.f, 0.f};
  }

  for (int t = 0; t < NT; ++t) {
    const int bo  = (t & 1) * BUFS;
    const int bo2 = ((t + 1) & 1) * BUFS;

    if (NSPLIT == 1 && t == NT - 1) asm volatile("s_waitcnt vmcnt(0)" ::: "memory");
    else                            asm volatile("s_waitcnt vmcnt(4)" ::: "memory");
    __builtin_amdgcn_s_barrier();
    __builtin_amdgcn_sched_barrier(0);

    if (NSPLIT == 3 && t + 1 < NT) {
      stg(ah, sgA, t + 1, AHO + bo2);
      stg(bh, sgB, t + 1, BHO + bo2);
    }

    bf16x8 a0[4][2], b0[2][2];
    #pragma unroll
    for (int m = 0; m < 4; ++m) {
      a0[m][0] = *(const bf16x8*)(smem + AHO + bo + fa + m * 2048 + kqx0);
      a0[m][1] = *(const bf16x8*)(smem + AHO + bo + fa + m * 2048 + kqx1);
    }
    #pragma unroll
    for (int n = 0; n < 2; ++n) {
      b0[n][0] = *(const bf16x8*)(smem + BHO + bo + fb + n * 2048 + kqx0);
      b0[n][1] = *(const bf16x8*)(smem + BHO + bo + fb + n * 2048 + kqx1);
    }
    __builtin_amdgcn_s_setprio(1);
    #pragma unroll
    for (int kq = 0; kq < 2; ++kq)
      #pragma unroll
      for (int m = 0; m < 4; ++m)
        #pragma unroll
        for (int n = 0; n < 2; ++n)
          acc[m][n] = mfma16(a0[m][kq], b0[n][kq], acc[m][n]);
    __builtin_amdgcn_s_setprio(0);
    asm volatile("s_waitcnt lgkmcnt(0)" ::: "memory");

    if constexpr (NSPLIT == 3) {
      if (t + 1 < NT) asm volatile("s_waitcnt vmcnt(4)" ::: "memory");
      else            asm volatile("s_waitcnt vmcnt(0)" ::: "memory");
      __builtin_amdgcn_s_barrier();
      __builtin_amdgcn_sched_barrier(0);

      if (t + 1 < NT) {
        stg(al, sgA, t + 1, ALO + bo2);
        stg(bl, sgB, t + 1, BLO + bo2);
      }
      bf16x8 a1[4][2], b1[2][2];
      #pragma unroll
      for (int m = 0; m < 4; ++m) {
        a1[m][0] = *(const bf16x8*)(smem + ALO + bo + fa + m * 2048 + kqx0);
        a1[m][1] = *(const bf16x8*)(smem + ALO + bo + fa + m * 2048 + kqx1);
      }
      #pragma unroll
      for (int n = 0; n < 2; ++n) {
        b1[n][0] = *(const bf16x8*)(smem + BLO + bo + fb + n * 2048 + kqx0);
        b1[n][1] = *(const bf16x8*)(smem + BLO + bo + fb + n * 2048 + kqx1);
      }
      __builtin_amdgcn_s_setprio(1);
      #pragma unroll
      for (int kq = 0; kq < 2; ++kq)
        #pragma unroll
        for (int m = 0; m < 4; ++m)
          #pragma unroll
          for (int n = 0; n < 2; ++n)
            acc[m][n] = mfma16(a1[m][kq], b0[n][kq], acc[m][n]);
      #pragma unroll
      for (int kq = 0; kq < 2; ++kq)
        #pragma unroll
        for (int m = 0; m < 4; ++m)
          #pragma unroll
          for (int n = 0; n < 2; ++n)
            acc[m][n] = mfma16(a0[m][kq], b1[n][kq], acc[m][n]);
      __builtin_amdgcn_s_setprio(0);
      asm volatile("s_waitcnt lgkmcnt(0)" ::: "memory");
    } else {
      __builtin_amdgcn_s_barrier();
      if (t + 2 < NT) {
        stg(ah, sgA, t + 2, AHO + bo);
        stg(bh, sgB, t + 2, BHO + bo);
      }
    }
  }

  const int l15 = lane & 15, g4 = (lane >> 4) << 2;
  const int colb = bcol0 + wc * 32 + l15;
  const float bi0 = bias[colb], bi1 = bias[colb + 16];
  #pragma unroll
  for (int m = 0; m < 4; ++m) {
    #pragma unroll
    for (int j = 0; j < 4; ++j) {
      const int row = arow0 + wr * 64 + m * 16 + g4 + j;
      float v0 = acc[m][0][j] + bi0, v1 = acc[m][1][j] + bi1;
      u16 h0 = f2bf(v0), h1 = f2bf(v1);
      ch[(size_t)row * KDIM + colb] = h0;
      ch[(size_t)row * KDIM + colb + 16] = h1;
      if constexpr (SPLITOUT) {
        cl[(size_t)row * KDIM + colb] = f2bf(v0 - bf2f(h0));
        cl[(size_t)row * KDIM + colb + 16] = f2bf(v1 - bf2f(h1));
      }
    }
  }
}

// ---------------------------------------------------------------------------
// Scores sweep, fine-phase schedule (T3+T4). 256x256 tile, BK=32, 8 waves
// (2Mx4N), wave out 128x64 (acc[8][4]). 4 LDS tile-slots of 32KB (A 16K +
// B 16K), slot = T&3. Iteration = 2 K-tiles (t,t+1), 4 phases:
//   p0: read t:{a0-7,b0-1}; stage A(t+2);             barrier; MFMA m*,n0-1
//   p1: read t:{b2-3};      stage B(t+2); vmcnt(4);   barrier; MFMA m*,n2-3
//   p2: read t+1 frags;     stage A(t+3);             barrier; MFMA
//   p3: read t+1:{b2-3};    stage B(t+3); vmcnt(4);   barrier; MFMA
// vmcnt(4) derivation (per-wave, 2 glds/phase): at p1 outstanding =
// prev{A(t+1),B(t+1)} + this{A(t+2),B(t+2)} = 8; <=4 retires exactly the
// units p2/p3 read. Symmetric at p3 for next iter's p0/p1. Never 0 mid-loop;
// final iteration drains (vmcnt 0). Slots read/written are disjoint per
// iteration -> no WAR drains. Swizzle: kslot^(row&3), glds dest linear.
// ---------------------------------------------------------------------------
__global__ __launch_bounds__(512, 2) void scores_kernel(
    const u16* __restrict__ fh, const u16* __restrict__ gh,
    const uint32_t* __restrict__ adjb, uint32_t* __restrict__ cand,
    int* __restrict__ cnts, int* rowmax)
{
  extern __shared__ char smem[];
  constexpr int NKT = 128;               // 4 key-tiles x 32 K-tiles (BK=32)

  const int tid = threadIdx.x, w = tid >> 6, lane = tid & 63;
  const int wr = w >> 2, wc = w & 3;
  const int l15 = lane & 15, g4 = (lane >> 4) << 2;

  // 256 wgs: XCD x hosts row-slabs x*4..x*4+3; 8 siblings per slab.
  const int xcd = blockIdx.x & 7, idx = blockIdx.x >> 3;
  const int bx  = xcd * 4 + (idx & 3);
  const int sub = idx >> 2;              // sibling 0..7
  const int arow0 = bx * 256;

  // ---- staging geometry: wave w stages rows [w*32,w*32+32), 2 glds per
  //      matrix per K-tile (16 rows x 64B each). Pre-swizzled global col.
  const int srA = w * 32 + (lane >> 2);
  const int scw = ((lane & 3) ^ ((lane >> 2) & 3)) * 8;
  const size_t gA0 = (size_t)(arow0 + srA) * KDIM + scw;
  const size_t gA1 = gA0 + (size_t)16 * KDIM;
  const size_t gB0 = (size_t)(sub * 256 + srA) * KDIM + scw;
  const size_t gB1 = gB0 + (size_t)16 * KDIM;
  const int ldsA = w * 2048;             // within slot A region (16KB)
  const int ldsB = 16384 + w * 2048;     // within slot B region

  auto stageA = [&](int T) {
    const int slot = (T & 3) * 32768;
    const int k0 = (T & 31) * 32;
    glds16(fh + gA0 + k0, smem + slot + ldsA);
    glds16(fh + gA1 + k0, smem + slot + ldsA + 1024);
  };
  auto stageB = [&](int T) {
    const int slot = (T & 3) * 32768;
    const size_t ko = (size_t)(T >> 5) * (2048 * KDIM) + (T & 31) * 32;
    glds16(gh + gB0 + ko, smem + slot + ldsB);
    glds16(gh + gB1 + ko, smem + slot + ldsB + 1024);
  };

  // ---- fragment read offsets: row*64B, phys kslot = g ^ (row&3)
  const int faoff = (wr * 128 + l15) * 64;
  const int fboff = 16384 + (wc * 64 + l15) * 64;
  const int kx = (((lane >> 4) ^ (lane & 3))) * 16;

  f32x4 acc[8][4];
  #pragma unroll
  for (int m = 0; m < 8; ++m)
    #pragma unroll
    for (int n = 0; n < 4; ++n) acc[m][n] = f32x4{0.f, 0.f, 0.f, 0.f};

  const unsigned long long lmask = (1ull << lane) - 1ull;
  const unsigned long long gm = 0xFFFFull << (lane & 48);

  // ---- prologue: stage tiles 0,1 and drain once
  stageA(0); stageB(0); stageA(1); stageB(1);
  asm volatile("s_waitcnt vmcnt(0)" ::: "memory");
  __builtin_amdgcn_s_barrier();

  bf16x8 a[8], b[4];

  for (int u = 0; u < NKT / 2; ++u) {
    const int t = 2 * u;
    const bool fin = (u == NKT / 2 - 1);
    const int s0 = (t & 3) * 32768, s1 = ((t + 1) & 3) * 32768;

    // ================= phase 0: tile t, quadrant n0-1 =================
    #pragma unroll
    for (int m = 0; m < 8; ++m)
      a[m] = *(const bf16x8*)(smem + s0 + faoff + m * 1024 + kx);
    b[0] = *(const bf16x8*)(smem + s0 + fboff + kx);
    b[1] = *(const bf16x8*)(smem + s0 + fboff + 1024 + kx);
    if (!fin) stageA(t + 2);
    __builtin_amdgcn_sched_barrier(0);
    __builtin_amdgcn_s_barrier();
    __builtin_amdgcn_s_setprio(1);
    #pragma unroll
    for (int m = 0; m < 8; ++m) {
      acc[m][0] = mfma16(a[m], b[0], acc[m][0]);
      acc[m][1] = mfma16(a[m], b[1], acc[m][1]);
    }
    __builtin_amdgcn_s_setprio(0);
    __builtin_amdgcn_sched_barrier(0);
    __builtin_amdgcn_s_barrier();

    // ================= phase 1: tile t, quadrant n2-3 =================
    b[2] = *(const bf16x8*)(smem + s0 + fboff + 2048 + kx);
    b[3] = *(const bf16x8*)(smem + s0 + fboff + 3072 + kx);
    if (!fin) stageB(t + 2);
    __builtin_amdgcn_sched_barrier(0);
    if (fin) asm volatile("s_waitcnt vmcnt(0)" ::: "memory");
    else     asm volatile("s_waitcnt vmcnt(4)" ::: "memory");
    __builtin_amdgcn_s_barrier();
    __builtin_amdgcn_s_setprio(1);
    #pragma unroll
    for (int m = 0; m < 8; ++m) {
      acc[m][2] = mfma16(a[m], b[2], acc[m][2]);
      acc[m][3] = mfma16(a[m], b[3], acc[m][3]);
    }
    __builtin_amdgcn_s_setprio(0);
    __builtin_amdgcn_sched_barrier(0);
    __builtin_amdgcn_s_barrier();

    // ================= phase 2: tile t+1, quadrant n0-1 ===============
    #pragma unroll
    for (int m = 0; m < 8; ++m)
      a[m] = *(const bf16x8*)(smem + s1 + faoff + m * 1024 + kx);
    b[0] = *(const bf16x8*)(smem + s1 + fboff + kx);
    b[1] = *(const bf16x8*)(smem + s1 + fboff + 1024 + kx);
    if (!fin) stageA(t + 3);
    __builtin_amdgcn_sched_barrier(0);
    __builtin_amdgcn_s_barrier();
    __builtin_amdgcn_s_setprio(1);
    #pragma unroll
    for (int m = 0; m < 8; ++m) {
      acc[m][0] = mfma16(a[m], b[0], acc[m][0]);
      acc[m][1] = mfma16(a[m], b[1], acc[m][1]);
    }
    __builtin_amdgcn_s_setprio(0);
    __builtin_amdgcn_sched_barrier(0);
    __builtin_amdgcn_s_barrier();

    // ================= phase 3: tile t+1, quadrant n2-3 ===============
    b[2] = *(const bf16x8*)(smem + s1 + fboff + 2048 + kx);
    b[3] = *(const bf16x8*)(smem + s1 + fboff + 3072 + kx);
    if (!fin) stageB(t + 3);
    __builtin_amdgcn_sched_barrier(0);
    if (fin) asm volatile("s_waitcnt vmcnt(0)" ::: "memory");
    else     asm volatile("s_waitcnt vmcnt(4)" ::: "memory");
    __builtin_amdgcn_s_barrier();
    __builtin_amdgcn_s_setprio(1);
    #pragma unroll
    for (int m = 0; m < 8; ++m) {
      acc[m][2] = mfma16(a[m], b[2], acc[m][2]);
      acc[m][3] = mfma16(a[m], b[3], acc[m][3]);
    }
    __builtin_amdgcn_s_setprio(0);
    __builtin_amdgcn_sched_barrier(0);
    asm volatile("s_waitcnt lgkmcnt(0)" ::: "memory");
    __builtin_amdgcn_s_barrier();

    // ================= key-tile epilogue (every 16 iterations) ========
    if (((t + 1) & 31) == 31) {
      const int it = (t + 1) >> 5;
      const int bcol0 = (sub + 8 * it) * 256;
      const int keyb = bcol0 + wc * 64 + l15;
      #pragma unroll
      for (int m = 0; m < 8; ++m) {
        #pragma unroll
        for (int j = 0; j < 4; ++j) {
          const int row = arow0 + wr * 128 + m * 16 + g4 + j;
          const uint32_t* ap = adjb + (size_t)row * (NROWS / 32) + (bcol0 >> 5) + wc * 2;
          const uint32_t w0 = ap[0], w1 = ap[1];
          float sv[4]; float rm = NEGBIG;
          #pragma unroll
          for (int n = 0; n < 4; ++n) {
            float v = fmaxf(acc[m][n][j], 0.f);
            uint32_t bit = ((n < 2 ? w0 : w1) >> ((n & 1) * 16 + l15)) & 1u;
            sv[n] = bit ? v : NEGBIG;
            rm = fmaxf(rm, sv[n]);
          }
          rm = fmaxf(rm, __shfl_xor(rm, 1));
          rm = fmaxf(rm, __shfl_xor(rm, 2));
          rm = fmaxf(rm, __shfl_xor(rm, 4));
          rm = fmaxf(rm, __shfl_xor(rm, 8));
          const float old = __int_as_float(rowmax[row]);   // stale-tolerant
          const float mr = fmaxf(rm, old);
          if (l15 == 0 && rm > old) atomicMax(rowmax + row, __float_as_int(rm));
          const float thr = mr - EMIT_THR;
          unsigned long long mm[4]; int c4[4];
          int tot = 0;
          #pragma unroll
          for (int n = 0; n < 4; ++n) {
            mm[n] = __ballot(sv[n] > thr);
            c4[n] = __popcll(mm[n] & gm);
            tot += c4[n];
          }
          int base = 0;
          if (l15 == 0 && tot > 0) base = atomicAdd(cnts + row, tot);
          base = __shfl(base, lane & 48);
          int pref = 0;
          #pragma unroll
          for (int n = 0; n < 4; ++n) {
            const int p = base + pref + __popcll(mm[n] & gm & lmask);
            if ((sv[n] > thr) && p < CAP)
              cand[(size_t)row * CAP + p] =
                  ((uint32_t)f2bf(sv[n]) << 16) | (uint32_t)(keyb + n * 16);
            pref += c4[n];
          }
        }
      }
      #pragma unroll
      for (int m = 0; m < 8; ++m)
        #pragma unroll
        for (int n = 0; n < 4; ++n) acc[m][n] = f32x4{0.f, 0.f, 0.f, 0.f};
    }
  }
}

// ---------------------------------------------------------------------------
// adj (int32 0/1, 268 MB) -> bitmask (8 MB). BW-bound single pass.
// ---------------------------------------------------------------------------
__global__ __launch_bounds__(256) void adjpack_kernel(
    const int* __restrict__ adj, uint32_t* __restrict__ adjb)
{
  size_t w = (size_t)blockIdx.x * 256 + threadIdx.x;
  const int* src = adj + (w << 5);
  uint32_t m = 0;
  #pragma unroll
  for (int j = 0; j < 8; ++j) {
    i32x4 v = *(const i32x4*)(src + j * 4);
    m |= (v[0] > 0 ? 1u : 0u) << (j * 4)
       | (v[1] > 0 ? 1u : 0u) << (j * 4 + 1)
       | (v[2] > 0 ? 1u : 0u) << (j * 4 + 2)
       | (v[3] > 0 ? 1u : 0u) << (j * 4 + 3);
  }
  adjb[w] = m;
}

// ---------------------------------------------------------------------------
// Finalize: survivors (within SURV_THR of approx max) rescored exactly in
// fp32 from (fh+fl, gh+gl); tail stays approx in the denominator only.
// ---------------------------------------------------------------------------
__global__ __launch_bounds__(256) void finalize_kernel(
    const uint32_t* __restrict__ cand, const int* __restrict__ cnts,
    const u16* __restrict__ fh, const u16* __restrict__ fl,
    const u16* __restrict__ gh, const u16* __restrict__ gl,
    const u16* __restrict__ vh, float* __restrict__ out)
{
  const int row = blockIdx.x, tid = threadIdx.x, wv = tid >> 6, lane = tid & 63;
  __shared__ float sS[CAP];
  __shared__ int sK[CAP];
  __shared__ float sF[KDIM];
  __shared__ float sEx[MAXS];
  __shared__ int sKs[MAXS];
  __shared__ float red[4];
  __shared__ int nsig;
  int cnt = cnts[row]; cnt = cnt < CAP ? cnt : CAP;
  const int col = tid * 4;
  if (cnt <= 0) {
    f32x4 z = {0.f, 0.f, 0.f, 0.f};
    *(f32x4*)(out + (size_t)row * KDIM + col) = z;
    return;
  }
  if (tid == 0) nsig = 0;
  {
    us4 h = *(const us4*)(fh + (size_t)row * KDIM + col);
    us4 l = *(const us4*)(fl + (size_t)row * KDIM + col);
    #pragma unroll
    for (int j = 0; j < 4; ++j) sF[col + j] = bf2f(h[j]) + bf2f(l[j]);
  }
  for (int i = tid; i < cnt; i += 256) {
    uint32_t pk = cand[(size_t)row * CAP + i];
    sS[i] = bf2f((u16)(pk >> 16));
    sK[i] = (int)(pk & 0xFFFFu);
  }
  __syncthreads();
  float lm = NEGBIG;
  for (int i = tid; i < cnt; i += 256) lm = fmaxf(lm, sS[i]);
  #pragma unroll
  for (int d = 1; d < 64; d <<= 1) lm = fmaxf(lm, __shfl_xor(lm, d));
  if ((tid & 63) == 0) red[tid >> 6] = lm;
  __syncthreads();
  const float am = fmaxf(fmaxf(red[0], red[1]), fmaxf(red[2], red[3]));
  __syncthreads();
  for (int i = tid; i < cnt; i += 256) {
    if (sS[i] > am - SURV_THR) {
      int p = atomicAdd(&nsig, 1);
      if (p < MAXS) { sKs[p] = sK[i]; sS[i] = NEGBIG; }
    }
  }
  __syncthreads();
  const int ns = nsig < MAXS ? nsig : MAXS;
  for (int si = wv; si < ns; si += 4) {
    const int key = sKs[si];
    const u16* grh = gh + (size_t)key * KDIM + lane * 16;
    const u16* grl = gl + (size_t)key * KDIM + lane * 16;
    float d = 0.f;
    #pragma unroll
    for (int u = 0; u < 4; ++u) {
      us4 h = *(const us4*)(grh + u * 4);
      us4 l = *(const us4*)(grl + u * 4);
      #pragma unroll
      for (int j = 0; j < 4; ++j)
        d += (bf2f(h[j]) + bf2f(l[j])) * sF[lane * 16 + u * 4 + j];
    }
    #pragma unroll
    for (int dd = 1; dd < 64; dd <<= 1) d += __shfl_xor(d, dd);
    if (lane == 0) sEx[si] = fmaxf(d, 0.f);
  }
  __syncthreads();
  float em = NEGBIG;
  for (int i = tid; i < ns; i += 256) em = fmaxf(em, sEx[i]);
  #pragma unroll
  for (int d = 1; d < 64; d <<= 1) em = fmaxf(em, __shfl_xor(em, d));
  if ((tid & 63) == 0) red[tid >> 6] = em;
  __syncthreads();
  const float m = fmaxf(fmaxf(red[0], red[1]), fmaxf(red[2], red[3]));
  __syncthreads();
  float ls = 0.f;
  for (int i = tid; i < cnt; i += 256) {
    float s = sS[i];
    if (s > NEGBIG * 0.5f) ls += __expf(s - m);
  }
  for (int i = tid; i < ns; i += 256) ls += __expf(sEx[i] - m);
  #pragma unroll
  for (int d = 1; d < 64; d <<= 1) ls += __shfl_xor(ls, d);
  if ((tid & 63) == 0) red[tid >> 6] = ls;
  __syncthreads();
  const float inv = 1.f / (red[0] + red[1] + red[2] + red[3]);
  float a0 = 0.f, a1 = 0.f, a2 = 0.f, a3 = 0.f;
  const u16* vbase = vh + col;
  for (int i = 0; i < ns; ++i) {
    const float wt = __expf(sEx[i] - m) * inv;
    us4 vv = *(const us4*)(vbase + (size_t)sKs[i] * KDIM);
    a0 += wt * bf2f(vv[0]); a1 += wt * bf2f(vv[1]);
    a2 += wt * bf2f(vv[2]); a3 += wt * bf2f(vv[3]);
  }
  f32x4 o = {a0, a1, a2, a3};
  *(f32x4*)(out + (size_t)row * KDIM + col) = o;
}

// ---------------------------------------------------------------------------
// Transpose + hi/lo split of a [K][N] fp32 weight into [N][K] bf16 pair.
// ---------------------------------------------------------------------------
__global__ __launch_bounds__(256) void wsplit_kernel(
    const float* __restrict__ W, u16* __restrict__ th, u16* __restrict__ tl)
{
  __shared__ float tile[32][33];
  const int bx = blockIdx.x, by = blockIdx.y;
  const int tx = threadIdx.x & 31, ty = threadIdx.x >> 5;
  #pragma unroll
  for (int i = 0; i < 4; ++i) {
    int ky = ty + i * 8;
    tile[ky][tx] = W[(size_t)(by * 32 + ky) * KDIM + bx * 32 + tx];
  }
  __syncthreads();
  #pragma unroll
  for (int i = 0; i < 4; ++i) {
    int ny = ty + i * 8;
    float v = tile[tx][ny];
    u16 h = f2bf(v);
    th[(size_t)(bx * 32 + ny) * KDIM + by * 32 + tx] = h;
    tl[(size_t)(bx * 32 + ny) * KDIM + by * 32 + tx] = f2bf(v - bf2f(h));
  }
}

__global__ __launch_bounds__(256) void xsplit_kernel(
    const float* __restrict__ x, u16* __restrict__ xh, u16* __restrict__ xl)
{
  size_t i = ((size_t)blockIdx.x * 256 + threadIdx.x) * 4;
  f32x4 v = *(const f32x4*)(x + i);
  us4 h, l;
  #pragma unroll
  for (int j = 0; j < 4; ++j) {
    h[j] = f2bf(v[j]);
    l[j] = f2bf(v[j] - bf2f(h[j]));
  }
  *(us4*)(xh + i) = h;
  *(us4*)(xl + i) = l;
}

__global__ void ws_report(float* out, size_t n, float v) {
  for (size_t i = (size_t)blockIdx.x * blockDim.x + threadIdx.x; i < n;
       i += (size_t)gridDim.x * blockDim.x) out[i] = v;
}

extern "C" void kernel_launch(void* const* d_in, const int* in_sizes, int n_in,
                              void* d_out, int out_size, void* d_ws, size_t ws_size,
                              hipStream_t stream) {
  (void)in_sizes; (void)n_in;
  const float* x   = (const float*)d_in[0];
  const int*   adj = (const int*)d_in[1];
  const float* Wf  = (const float*)d_in[2];
  const float* bf_ = (const float*)d_in[3];
  const float* Wg  = (const float*)d_in[4];
  const float* bg_ = (const float*)d_in[5];
  const float* W   = (const float*)d_in[6];
  const float* bW_ = (const float*)d_in[7];

  char* p = (char*)d_ws;
  const size_t ND2 = (size_t)NROWS * KDIM * 2;
  const size_t W2  = (size_t)KDIM * KDIM * 2;
  u16* xh = (u16*)p;  p += ND2;
  u16* xl = (u16*)p;  p += ND2;
  u16* fh = (u16*)p;  p += ND2;
  u16* fl = (u16*)p;  p += ND2;
  u16* gh = (u16*)p;  p += ND2;
  u16* gl = (u16*)p;  p += ND2;
  u16* vh = (u16*)p;  p += ND2;
  u16* wfh = (u16*)p; p += W2;
  u16* wfl = (u16*)p; p += W2;
  u16* wgh = (u16*)p; p += W2;
  u16* wgl = (u16*)p; p += W2;
  u16* wh  = (u16*)p; p += W2;
  u16* wl  = (u16*)p; p += W2;
  uint32_t* cand = (uint32_t*)p; p += (size_t)NROWS * CAP * 4;
  int* cnts   = (int*)p; p += (size_t)NROWS * 4;
  int* rowmax = (int*)p; p += (size_t)NROWS * 4;
  const size_t need = (size_t)(p - (char*)d_ws);
  if (ws_size < need) {
    ws_report<<<256, 256, 0, stream>>>((float*)d_out, (size_t)out_size, (float)ws_size);
    return;
  }
  uint32_t* adjb = (uint32_t*)xl;   // aliases xl after pre-GEMMs are done

  auto kf = gemm_kernel<3, true>;
  auto kv = gemm_kernel<1, false>;
  hipFuncSetAttribute((const void*)kf, hipFuncAttributeMaxDynamicSharedMemorySize, 131072);
  hipFuncSetAttribute((const void*)kv, hipFuncAttributeMaxDynamicSharedMemorySize, 65536);
  hipFuncSetAttribute((const void*)scores_kernel, hipFuncAttributeMaxDynamicSharedMemorySize, 131072);

  hipMemsetAsync(cnts, 0, (size_t)NROWS * 8, stream);   // cnts + rowmax (0 == 0.0f)
  wsplit_kernel<<<dim3(32, 32), 256, 0, stream>>>(Wf, wfh, wfl);
  wsplit_kernel<<<dim3(32, 32), 256, 0, stream>>>(Wg, wgh, wgl);
  wsplit_kernel<<<dim3(32, 32), 256, 0, stream>>>(W, wh, wl);
  xsplit_kernel<<<(NROWS * KDIM) / (256 * 4), 256, 0, stream>>>(x, xh, xl);

  // f = x@Wf + bf, g = x@Wg + bg (split-3, hi+lo out), v = x@W + bW (1 pass)
  kf<<<dim3(64, 8), 512, 131072, stream>>>(xh, xl, wfh, wfl, bf_, fh, fl);
  kf<<<dim3(64, 8), 512, 131072, stream>>>(xh, xl, wgh, wgl, bg_, gh, gl);
  kv<<<dim3(64, 8), 512, 65536, stream>>>(xh, xl, wh, wl, bW_, vh, nullptr);
  adjpack_kernel<<<(NROWS * (NROWS / 32)) / 256, 256, 0, stream>>>(adj, adjb);
  // fine-phase 256x256 scores sweep + bounded candidate emission
  scores_kernel<<<dim3(256), 512, 131072, stream>>>(fh, gh, adjb, cand, cnts, rowmax);
  // exact rescoring of survivors + softmax + v gather
  finalize_kernel<<<NROWS, 256, 0, stream>>>(cand, cnts, fh, fl, gh, gl, vh,
                                             (float*)d_out);
}